// Round 2
// baseline (6459.514 us; speedup 1.0000x reference)
//
#include <hip/hip_runtime.h>
#include <math.h>

#define HD 128

__device__ __forceinline__ float sigf(float v) { return 1.0f / (1.0f + __expf(-v)); }

// zero na4 float4s at a, then nb floats at b
__global__ __launch_bounds__(256) void zero2_k(float4* __restrict__ a, long long na4,
                                               float* __restrict__ b, long long nb) {
  long long t = (long long)blockIdx.x * 256 + threadIdx.x;
  if (t < na4) {
    a[t] = make_float4(0.f, 0.f, 0.f, 0.f);
  } else if (t - na4 < nb) {
    b[t - na4] = 0.f;
  }
}

// C[nrows,M] = op(A)[nrows,128] @ B' + bias1 + bias2
//   BTRANS=1: B is [Mb,128] row-major (use B[j,k])  -> C = A @ B^T
//   BTRANS=0: B is [128,M] row-major (use B[k,j])  -> C = A @ B
//   LSTMMAP : output col c maps to B-row (c<128 ? c : c+128) (selects i,g,o of [512,128])
//   ASCALE  : scale A row r by 1/max(deg[r],1)
// Tile 64x64, 256 threads, 4x4 per thread. K=128: A staged fully, B in 2 halves.
template <bool BTRANS, bool LSTMMAP, bool ASCALE>
__global__ __launch_bounds__(256) void gemm_k(
    const float* __restrict__ A, const float* __restrict__ B,
    const float* __restrict__ bias1, const float* __restrict__ bias2,
    const float* __restrict__ deg, float* __restrict__ C, int nrows, int M) {
  __shared__ float As[64][132];  // [r][k]; stride 132 keeps float4 reads conflict-free
  __shared__ float Bs[64][64];   // [k_local][c]
  const int tid = threadIdx.x;
  const int tx = tid & 15, ty = tid >> 4;
  const int row0 = blockIdx.y * 64;
  const int col0 = blockIdx.x * 64;

#pragma unroll
  for (int it = 0; it < 8; ++it) {
    int idx = it * 256 + tid;
    int r = idx >> 5, kq = idx & 31;
    int gr = row0 + r;
    float4 v = make_float4(0.f, 0.f, 0.f, 0.f);
    if (gr < nrows) {
      v = reinterpret_cast<const float4*>(A)[(size_t)gr * (HD / 4) + kq];
      if (ASCALE) {
        float s = 1.0f / fmaxf(deg[gr], 1.0f);
        v.x *= s; v.y *= s; v.z *= s; v.w *= s;
      }
    }
    *reinterpret_cast<float4*>(&As[r][kq * 4]) = v;
  }

  float acc[4][4] = {};

  for (int half = 0; half < 2; ++half) {
    __syncthreads();
    if (BTRANS) {
#pragma unroll
      for (int it = 0; it < 4; ++it) {
        int idx = it * 256 + tid;
        int c = idx & 63, kq = idx >> 6;  // kq 0..15 within half
        int gc = col0 + c;
        int jm = LSTMMAP ? (gc < 128 ? gc : gc + 128) : gc;
        float4 v = reinterpret_cast<const float4*>(B)[(size_t)jm * (HD / 4) + half * 16 + kq];
        Bs[kq * 4 + 0][c] = v.x;
        Bs[kq * 4 + 1][c] = v.y;
        Bs[kq * 4 + 2][c] = v.z;
        Bs[kq * 4 + 3][c] = v.w;
      }
    } else {
#pragma unroll
      for (int it = 0; it < 4; ++it) {
        int idx = it * 256 + tid;
        int cq = idx & 15, kl = idx >> 4;  // kl 0..63 within half
        float4 v = reinterpret_cast<const float4*>(B)[((size_t)(half * 64 + kl) * M + col0) / 4 + cq];
        *reinterpret_cast<float4*>(&Bs[kl][cq * 4]) = v;
      }
    }
    __syncthreads();

#pragma unroll
    for (int kk = 0; kk < 16; ++kk) {
      float4 a[4], b[4];
#pragma unroll
      for (int j = 0; j < 4; ++j)
        a[j] = *reinterpret_cast<const float4*>(&As[ty * 4 + j][half * 64 + kk * 4]);
#pragma unroll
      for (int l = 0; l < 4; ++l)
        b[l] = *reinterpret_cast<const float4*>(&Bs[kk * 4 + l][tx * 4]);
#pragma unroll
      for (int j = 0; j < 4; ++j) {
        const float av[4] = {a[j].x, a[j].y, a[j].z, a[j].w};
#pragma unroll
        for (int kl = 0; kl < 4; ++kl) {
          acc[j][0] += av[kl] * b[kl].x;
          acc[j][1] += av[kl] * b[kl].y;
          acc[j][2] += av[kl] * b[kl].z;
          acc[j][3] += av[kl] * b[kl].w;
        }
      }
    }
  }

  float badd[4];
#pragma unroll
  for (int l = 0; l < 4; ++l) {
    int gc = col0 + tx * 4 + l;
    int jm = LSTMMAP ? (gc < 128 ? gc : gc + 128) : gc;
    float bsum = 0.f;
    if (bias1) bsum += bias1[jm];
    if (bias2) bsum += bias2[jm];
    badd[l] = bsum;
  }
#pragma unroll
  for (int j = 0; j < 4; ++j) {
    int gr = row0 + ty * 4 + j;
    if (gr < nrows) {
      float4 o = make_float4(acc[j][0] + badd[0], acc[j][1] + badd[1],
                             acc[j][2] + badd[2], acc[j][3] + badd[3]);
      reinterpret_cast<float4*>(C)[((size_t)gr * M + col0) / 4 + tx] = o;
    }
  }
}

// 32 lanes per edge: coalesced 512B gather from m[src], fp32 HW atomics into agg[dst].
__global__ __launch_bounds__(256) void scatter_k(const int* __restrict__ ei,
                                                 const float* __restrict__ m,
                                                 float* __restrict__ agg,
                                                 float* __restrict__ deg, int E, int N) {
  long long gid = (long long)blockIdx.x * 256 + threadIdx.x;
  int e = (int)(gid >> 5);
  if (e >= E) return;
  int l = (int)(gid & 31);
  int s = ei[e];
  int d = ei[(size_t)E + e];
  if ((unsigned)s >= (unsigned)N || (unsigned)d >= (unsigned)N) return;  // crash guard
  float4 v = reinterpret_cast<const float4*>(m)[(size_t)s * (HD / 4) + l];
  float* a = agg + (size_t)d * HD + (size_t)l * 4;
  unsafeAtomicAdd(a + 0, v.x);
  unsafeAtomicAdd(a + 1, v.y);
  unsafeAtomicAdd(a + 2, v.z);
  unsafeAtomicAdd(a + 3, v.w);
  if (l == 0) unsafeAtomicAdd(deg + d, 1.0f);
}

__global__ __launch_bounds__(256) void ew_gru(const float* __restrict__ gi,
                                              const float* __restrict__ gh,
                                              const float* __restrict__ x,
                                              float* __restrict__ hconv, int total) {
  int t = blockIdx.x * 256 + threadIdx.x;
  if (t >= total) return;
  int i = t >> 7, c = t & 127;
  size_t b = (size_t)i * 384 + c;
  float r = sigf(gi[b] + gh[b]);
  float z = sigf(gi[b + 128] + gh[b + 128]);
  float n = tanhf(gi[b + 256] + r * gh[b + 256]);
  hconv[t] = (1.f - z) * n + z * x[t];
}

__global__ __launch_bounds__(256) void ew_lstm(const float* __restrict__ g3,
                                               float* __restrict__ out, int total) {
  int t = blockIdx.x * 256 + threadIdx.x;
  if (t >= total) return;
  int i = t >> 7, c = t & 127;
  size_t b = (size_t)i * 384 + c;
  float ig = g3[b], gg = g3[b + 128], og = g3[b + 256];
  float cc = sigf(ig) * tanhf(gg);
  float h = sigf(og) * tanhf(cc);
  out[t] = fmaxf(h, 0.f);
}

extern "C" void kernel_launch(void* const* d_in, const int* in_sizes, int n_in,
                              void* d_out, int out_size, void* d_ws, size_t ws_size,
                              hipStream_t stream) {
  const float* x = (const float*)d_in[0];
  const int* ei = (const int*)d_in[1];  // [2,E] int32 per harness contract
  const float* W = (const float*)d_in[2];
  const float* gw_ih = (const float*)d_in[3];
  const float* gw_hh = (const float*)d_in[4];
  const float* gb_ih = (const float*)d_in[5];
  const float* gb_hh = (const float*)d_in[6];
  const float* lw_ih = (const float*)d_in[7];
  // d_in[8] = lstm_w_hh: unused (h0 == 0). d_in[9]/[10] = lstm biases.
  const float* lb_ih = (const float*)d_in[9];
  const float* lb_hh = (const float*)d_in[10];
  float* out = (float*)d_out;

  const int N = in_sizes[0] / HD;
  const int E = in_sizes[1] / 2;

  const size_t nH = (size_t)N * HD;       // N*128
  const size_t N4 = (size_t)((N + 3) & ~3);

  // Resident scratch in ws: [m : nH][deg : N4]; agg lives in d_out (same size nH).
  // Per-chunk gate buffers G1/G2 (Nc*384 each) follow.
  float* ws = (float*)d_ws;
  float* m = ws;
  float* deg = m + nH;
  float* gbuf = deg + N4;

  // Adaptive chunk size from ws_size (fixed per problem size -> graph-safe).
  size_t F = ws_size / sizeof(float);
  size_t used = nH + N4;
  long long rem = (F > used + 16) ? (long long)(F - used - 16) : 0;
  long long ncl = rem / 768;  // two Nc*384 buffers
  int Nc;
  if (ncl >= N) {
    Nc = N;
  } else {
    Nc = (int)(ncl & ~63LL);
    if (Nc < 64) Nc = 64;  // floor; below this ws is unusably small anyway
  }

  float* agg = out;  // aliased: consumed (per-row) before out rows are written

  dim3 blk(256);

  // zero agg (nH float4-able) + deg
  {
    long long na4 = (long long)(nH / 4), nb = (long long)N4;
    long long tt = na4 + nb;
    zero2_k<<<(unsigned)((tt + 255) / 256), blk, 0, stream>>>(
        (float4*)agg, na4, deg, nb);
  }

  // m = x @ W   (NN, full N)
  gemm_k<false, false, false><<<dim3(HD / 64, (N + 63) / 64), blk, 0, stream>>>(
      x, W, nullptr, nullptr, nullptr, m, N, HD);

  // aggregation: agg += m[src] at dst; deg counts
  long long sthreads = (long long)E * 32;
  scatter_k<<<(unsigned)((sthreads + 255) / 256), blk, 0, stream>>>(ei, m, agg, deg, E, N);

  // chunked gate GEMMs + elementwise
  for (int r0 = 0; r0 < N; r0 += Nc) {
    int rows = (N - r0 < Nc) ? (N - r0) : Nc;
    float* G1 = gbuf;                       // gi, then reused as g3
    float* G2 = gbuf + (size_t)Nc * 384;    // gh
    float* hconv = m + (size_t)r0 * HD;     // m rows dead after scatter
    dim3 grows((unsigned)((rows + 63) / 64));
    int total = rows * HD;

    // gi = (agg/deg)[chunk] @ gru_w_ih^T + b_ih
    gemm_k<true, false, true><<<dim3(384 / 64, grows.x), blk, 0, stream>>>(
        agg + (size_t)r0 * HD, gw_ih, gb_ih, nullptr, deg + r0, G1, rows, 384);

    // gh = x[chunk] @ gru_w_hh^T + b_hh
    gemm_k<true, false, false><<<dim3(384 / 64, grows.x), blk, 0, stream>>>(
        x + (size_t)r0 * HD, gw_hh, gb_hh, nullptr, nullptr, G2, rows, 384);

    // GRU elementwise -> h_conv
    ew_gru<<<(total + 255) / 256, blk, 0, stream>>>(
        G1, G2, x + (size_t)r0 * HD, hconv, total);

    // LSTM gates (i,g,o; f dead since c0=0): g3 = hconv @ sel(lstm_w_ih)^T + b_ih + b_hh
    gemm_k<true, true, false><<<dim3(384 / 64, grows.x), blk, 0, stream>>>(
        hconv, lw_ih, lb_ih, lb_hh, nullptr, G1, rows, 384);

    // LSTM elementwise + relu -> out[chunk] (overwrites agg rows already consumed)
    ew_lstm<<<(total + 255) / 256, blk, 0, stream>>>(G1, out + (size_t)r0 * HD, total);
  }
}

// Round 5
// 1721.942 us; speedup vs baseline: 3.7513x; 3.7513x over previous
//
#include <hip/hip_runtime.h>
#include <math.h>

#define HD 128

__device__ __forceinline__ float sigf(float v) { return 1.0f / (1.0f + __expf(-v)); }

// zero n int32s
__global__ __launch_bounds__(256) void zeroi_k(int* __restrict__ p, int n) {
  int t = blockIdx.x * 256 + threadIdx.x;
  if (t < n) p[t] = 0;
}

// per-edge degree count
__global__ __launch_bounds__(256) void count_k(const int* __restrict__ ei,
                                               int* __restrict__ degcnt, int E, int N) {
  int e = blockIdx.x * 256 + threadIdx.x;
  if (e >= E) return;
  int d = ei[(size_t)E + e];
  if ((unsigned)d >= (unsigned)N) return;
  atomicAdd(&degcnt[d], 1);
}

// single-workgroup exclusive scan: degcnt[N] -> rowstart[N+1]; cursor = rowstart
// rowstart and cursor are DISTINCT allocations (rowstart has N+1 entries).
__global__ __launch_bounds__(1024) void scan_k(const int* __restrict__ degcnt,
                                               int* __restrict__ rowstart,
                                               int* __restrict__ cursor, int N) {
  __shared__ int tsum[1024];
  const int t = threadIdx.x;
  const int C = (N + 1023) / 1024;
  const int lo = t * C;
  const int hi = (lo + C < N) ? lo + C : N;
  int s = 0;
  for (int i = lo; i < hi; ++i) s += degcnt[i];
  tsum[t] = s;
  __syncthreads();
  // Hillis-Steele inclusive scan over 1024 thread sums
  for (int off = 1; off < 1024; off <<= 1) {
    int v = (t >= off) ? tsum[t - off] : 0;
    __syncthreads();
    tsum[t] += v;
    __syncthreads();
  }
  int run = tsum[t] - s;  // exclusive prefix for this thread's chunk
  for (int i = lo; i < hi; ++i) {
    rowstart[i] = run;
    cursor[i] = run;
    run += degcnt[i];
  }
  if (t == 1023) rowstart[N] = tsum[1023];
}

// per-edge bucket fill: csr[pos] = src
__global__ __launch_bounds__(256) void fill_k(const int* __restrict__ ei,
                                              int* __restrict__ cursor,
                                              int* __restrict__ csr, int E, int N) {
  int e = blockIdx.x * 256 + threadIdx.x;
  if (e >= E) return;
  int s = ei[e];
  int d = ei[(size_t)E + e];
  if ((unsigned)s >= (unsigned)N || (unsigned)d >= (unsigned)N) return;
  int pos = atomicAdd(&cursor[d], 1);
  csr[pos] = s;
}

// one wave per dst node: xagg[d] = mean over incoming edges of x[src]
// (mean commutes with the linear W map: mean(x@W) = mean(x)@W)
// lane holds float2 (64 lanes x 8B = 512B row)
__global__ __launch_bounds__(256) void gather_x_k(const int* __restrict__ csr,
                                                  const int* __restrict__ rowstart,
                                                  const float* __restrict__ x,
                                                  float* __restrict__ xagg, int N) {
  int w = (int)(((long long)blockIdx.x * 256 + threadIdx.x) >> 6);
  if (w >= N) return;
  int lane = threadIdx.x & 63;
  int beg = rowstart[w], end = rowstart[w + 1];
  const float2* x2 = reinterpret_cast<const float2*>(x);
  float ax = 0.f, ay = 0.f;
  int j = beg;
  for (; j + 4 <= end; j += 4) {
    int s0 = csr[j], s1 = csr[j + 1], s2 = csr[j + 2], s3 = csr[j + 3];
    float2 v0 = x2[(size_t)s0 * 64 + lane];
    float2 v1 = x2[(size_t)s1 * 64 + lane];
    float2 v2 = x2[(size_t)s2 * 64 + lane];
    float2 v3 = x2[(size_t)s3 * 64 + lane];
    ax += v0.x + v1.x + v2.x + v3.x;
    ay += v0.y + v1.y + v2.y + v3.y;
  }
  for (; j < end; ++j) {
    int s = csr[j];
    float2 v = x2[(size_t)s * 64 + lane];
    ax += v.x;
    ay += v.y;
  }
  float scale = 1.0f / fmaxf((float)(end - beg), 1.0f);
  reinterpret_cast<float2*>(xagg)[(size_t)w * 64 + lane] = make_float2(ax * scale, ay * scale);
}

// C[nrows,M] = A[nrows,128] @ B' + bias1 + bias2
//   BTRANS=1: B is [Mb,128] row-major -> C = A @ B^T
//   BTRANS=0: B is [128,M] row-major -> C = A @ B
//   LSTMMAP : output col c maps to B-row (c<128 ? c : c+128) (selects i,g,o of [512,128])
// Tile 64x64, 256 threads, 4x4 per thread. K=128: A staged fully, B in 2 halves.
template <bool BTRANS, bool LSTMMAP>
__global__ __launch_bounds__(256) void gemm_k(
    const float* __restrict__ A, const float* __restrict__ B,
    const float* __restrict__ bias1, const float* __restrict__ bias2,
    float* __restrict__ C, int nrows, int M) {
  __shared__ float As[64][132];  // [r][k]; stride 132 keeps float4 reads conflict-free
  __shared__ float Bs[64][64];   // [k_local][c]
  const int tid = threadIdx.x;
  const int tx = tid & 15, ty = tid >> 4;
  const int row0 = blockIdx.y * 64;
  const int col0 = blockIdx.x * 64;

#pragma unroll
  for (int it = 0; it < 8; ++it) {
    int idx = it * 256 + tid;
    int r = idx >> 5, kq = idx & 31;
    int gr = row0 + r;
    float4 v = make_float4(0.f, 0.f, 0.f, 0.f);
    if (gr < nrows) v = reinterpret_cast<const float4*>(A)[(size_t)gr * (HD / 4) + kq];
    *reinterpret_cast<float4*>(&As[r][kq * 4]) = v;
  }

  float acc[4][4] = {};

  for (int half = 0; half < 2; ++half) {
    __syncthreads();
    if (BTRANS) {
#pragma unroll
      for (int it = 0; it < 4; ++it) {
        int idx = it * 256 + tid;
        int c = idx & 63, kq = idx >> 6;  // kq 0..15 within half
        int gc = col0 + c;
        int jm = LSTMMAP ? (gc < 128 ? gc : gc + 128) : gc;
        float4 v = reinterpret_cast<const float4*>(B)[(size_t)jm * (HD / 4) + half * 16 + kq];
        Bs[kq * 4 + 0][c] = v.x;
        Bs[kq * 4 + 1][c] = v.y;
        Bs[kq * 4 + 2][c] = v.z;
        Bs[kq * 4 + 3][c] = v.w;
      }
    } else {
#pragma unroll
      for (int it = 0; it < 4; ++it) {
        int idx = it * 256 + tid;
        int cq = idx & 15, kl = idx >> 4;  // kl 0..63 within half
        float4 v = reinterpret_cast<const float4*>(B)[((size_t)(half * 64 + kl) * M + col0) / 4 + cq];
        *reinterpret_cast<float4*>(&Bs[kl][cq * 4]) = v;
      }
    }
    __syncthreads();

#pragma unroll
    for (int kk = 0; kk < 16; ++kk) {
      float4 a[4], b[4];
#pragma unroll
      for (int j = 0; j < 4; ++j)
        a[j] = *reinterpret_cast<const float4*>(&As[ty * 4 + j][half * 64 + kk * 4]);
#pragma unroll
      for (int l = 0; l < 4; ++l)
        b[l] = *reinterpret_cast<const float4*>(&Bs[kk * 4 + l][tx * 4]);
#pragma unroll
      for (int j = 0; j < 4; ++j) {
        const float av[4] = {a[j].x, a[j].y, a[j].z, a[j].w};
#pragma unroll
        for (int kl = 0; kl < 4; ++kl) {
          acc[j][0] += av[kl] * b[kl].x;
          acc[j][1] += av[kl] * b[kl].y;
          acc[j][2] += av[kl] * b[kl].z;
          acc[j][3] += av[kl] * b[kl].w;
        }
      }
    }
  }

  float badd[4];
#pragma unroll
  for (int l = 0; l < 4; ++l) {
    int gc = col0 + tx * 4 + l;
    int jm = LSTMMAP ? (gc < 128 ? gc : gc + 128) : gc;
    float bsum = 0.f;
    if (bias1) bsum += bias1[jm];
    if (bias2) bsum += bias2[jm];
    badd[l] = bsum;
  }
#pragma unroll
  for (int j = 0; j < 4; ++j) {
    int gr = row0 + ty * 4 + j;
    if (gr < nrows) {
      float4 o = make_float4(acc[j][0] + badd[0], acc[j][1] + badd[1],
                             acc[j][2] + badd[2], acc[j][3] + badd[3]);
      reinterpret_cast<float4*>(C)[((size_t)gr * M + col0) / 4 + tx] = o;
    }
  }
}

__global__ __launch_bounds__(256) void ew_gru(const float* __restrict__ gi,
                                              const float* __restrict__ gh,
                                              const float* __restrict__ x,
                                              float* __restrict__ hconv, int total) {
  int t = blockIdx.x * 256 + threadIdx.x;
  if (t >= total) return;
  int i = t >> 7, c = t & 127;
  size_t b = (size_t)i * 384 + c;
  float r = sigf(gi[b] + gh[b]);
  float z = sigf(gi[b + 128] + gh[b + 128]);
  float n = tanhf(gi[b + 256] + r * gh[b + 256]);
  hconv[t] = (1.f - z) * n + z * x[t];
}

__global__ __launch_bounds__(256) void ew_lstm(const float* __restrict__ g3,
                                               float* __restrict__ out, int total) {
  int t = blockIdx.x * 256 + threadIdx.x;
  if (t >= total) return;
  int i = t >> 7, c = t & 127;
  size_t b = (size_t)i * 384 + c;
  float ig = g3[b], gg = g3[b + 128], og = g3[b + 256];
  float cc = sigf(ig) * tanhf(gg);
  float h = sigf(og) * tanhf(cc);
  out[t] = fmaxf(h, 0.f);
}

extern "C" void kernel_launch(void* const* d_in, const int* in_sizes, int n_in,
                              void* d_out, int out_size, void* d_ws, size_t ws_size,
                              hipStream_t stream) {
  const float* x = (const float*)d_in[0];
  const int* ei = (const int*)d_in[1];  // [2,E] int32
  const float* W = (const float*)d_in[2];
  const float* gw_ih = (const float*)d_in[3];
  const float* gw_hh = (const float*)d_in[4];
  const float* gb_ih = (const float*)d_in[5];
  const float* gb_hh = (const float*)d_in[6];
  const float* lw_ih = (const float*)d_in[7];
  // d_in[8] = lstm_w_hh: unused (h0 == 0)
  const float* lb_ih = (const float*)d_in[9];
  const float* lb_hh = (const float*)d_in[10];
  float* out = (float*)d_out;

  const int N = in_sizes[0] / HD;
  const int E = in_sizes[1] / 2;

  const size_t N4 = (size_t)((N + 7) & ~7);       // degcnt / cursor
  const size_t N4p = (size_t)((N + 1 + 7) & ~7);  // rowstart: >= N+1 (no aliasing!)
  const size_t E4 = (size_t)((E + 3) & ~3);

  // ws layout (ints first, then float chunk buffers):
  // [degcnt:N4][rowstart:N4p][cursor:N4][csr:E4][Ac:Nc*128][G1:Nc*384][G2:Nc*384]
  int* degcnt = (int*)d_ws;
  int* rowstart = degcnt + N4;
  int* cursor = rowstart + N4p;
  int* csr = cursor + N4;
  float* fbuf = (float*)(csr + E4);

  // Adaptive chunk size from ws_size (fixed per problem -> graph-safe).
  size_t F = ws_size / sizeof(float);
  size_t used = N4 + N4p + N4 + E4;
  long long rem = (F > used + 16) ? (long long)(F - used - 16) : 0;
  long long ncl = rem / 896;  // Ac(128) + G1(384) + G2(384) per row
  int Nc;
  if (ncl >= N) {
    Nc = N;
  } else {
    Nc = (int)(ncl & ~63LL);
    if (Nc < 64) Nc = 64;
  }

  float* xagg = out;  // aliased: xagg rows consumed before out rows are written

  dim3 blk(256);

  // ---- CSR build ----
  zeroi_k<<<(unsigned)((N4 + 255) / 256), blk, 0, stream>>>(degcnt, (int)N4);
  count_k<<<(unsigned)((E + 255) / 256), blk, 0, stream>>>(ei, degcnt, E, N);
  scan_k<<<1, 1024, 0, stream>>>(degcnt, rowstart, cursor, N);
  fill_k<<<(unsigned)((E + 255) / 256), blk, 0, stream>>>(ei, cursor, csr, E, N);

  // ---- xagg = mean of x[src] per dst ----
  long long gthreads = (long long)N * 64;
  gather_x_k<<<(unsigned)((gthreads + 255) / 256), blk, 0, stream>>>(csr, rowstart, x, xagg, N);

  // ---- chunked: Ac = xagg@W; gi = Ac@gw_ih^T; gh = x@gw_hh^T; GRU; LSTM ----
  for (int r0 = 0; r0 < N; r0 += Nc) {
    int rows = (N - r0 < Nc) ? (N - r0) : Nc;
    float* Ac = fbuf;                    // agg chunk, then hconv
    float* G1 = Ac + (size_t)Nc * HD;    // gi, then g3
    float* G2 = G1 + (size_t)Nc * 384;   // gh
    dim3 grows((unsigned)((rows + 63) / 64));
    int total = rows * HD;

    // Ac = xagg[chunk] @ W (NN)
    gemm_k<false, false><<<dim3(HD / 64, grows.x), blk, 0, stream>>>(
        xagg + (size_t)r0 * HD, W, nullptr, nullptr, Ac, rows, HD);

    // gi = Ac @ gru_w_ih^T + b_ih
    gemm_k<true, false><<<dim3(384 / 64, grows.x), blk, 0, stream>>>(
        Ac, gw_ih, gb_ih, nullptr, G1, rows, 384);

    // gh = x[chunk] @ gru_w_hh^T + b_hh
    gemm_k<true, false><<<dim3(384 / 64, grows.x), blk, 0, stream>>>(
        x + (size_t)r0 * HD, gw_hh, gb_hh, nullptr, G2, rows, 384);

    // GRU elementwise -> hconv (reuses Ac; Ac dead after gi GEMM)
    ew_gru<<<(total + 255) / 256, blk, 0, stream>>>(
        G1, G2, x + (size_t)r0 * HD, Ac, total);

    // LSTM gates (i,g,o; f dead since c0=0): g3 = hconv @ sel(lstm_w_ih)^T + b_ih + b_hh
    gemm_k<true, true><<<dim3(384 / 64, grows.x), blk, 0, stream>>>(
        Ac, lw_ih, lb_ih, lb_hh, G1, rows, 384);

    // LSTM elementwise + relu -> out[chunk] (xagg rows already consumed)
    ew_lstm<<<(total + 255) / 256, blk, 0, stream>>>(G1, out + (size_t)r0 * HD, total);
  }
}

// Round 6
// 1321.711 us; speedup vs baseline: 4.8872x; 1.3028x over previous
//
#include <hip/hip_runtime.h>
#include <math.h>

#define HD 128

typedef __attribute__((ext_vector_type(8))) short short8;
typedef __attribute__((ext_vector_type(4))) float f32x4;

__device__ __forceinline__ float sigf(float v) { return 1.0f / (1.0f + __expf(-v)); }

// round-to-nearest-even fp32 -> bf16 bits
__device__ __forceinline__ unsigned short f2bf(float f) {
  union { float f; unsigned u; } v; v.f = f;
  unsigned r = (v.u + 0x7fffu + ((v.u >> 16) & 1u)) >> 16;
  return (unsigned short)r;
}

// ---------------- CSR build (unchanged from round 5) ----------------

__global__ __launch_bounds__(256) void zeroi_k(int* __restrict__ p, int n) {
  int t = blockIdx.x * 256 + threadIdx.x;
  if (t < n) p[t] = 0;
}

__global__ __launch_bounds__(256) void count_k(const int* __restrict__ ei,
                                               int* __restrict__ degcnt, int E, int N) {
  int e = blockIdx.x * 256 + threadIdx.x;
  if (e >= E) return;
  int d = ei[(size_t)E + e];
  if ((unsigned)d >= (unsigned)N) return;
  atomicAdd(&degcnt[d], 1);
}

__global__ __launch_bounds__(1024) void scan_k(const int* __restrict__ degcnt,
                                               int* __restrict__ rowstart,
                                               int* __restrict__ cursor, int N) {
  __shared__ int tsum[1024];
  const int t = threadIdx.x;
  const int C = (N + 1023) / 1024;
  const int lo = t * C;
  const int hi = (lo + C < N) ? lo + C : N;
  int s = 0;
  for (int i = lo; i < hi; ++i) s += degcnt[i];
  tsum[t] = s;
  __syncthreads();
  for (int off = 1; off < 1024; off <<= 1) {
    int v = (t >= off) ? tsum[t - off] : 0;
    __syncthreads();
    tsum[t] += v;
    __syncthreads();
  }
  int run = tsum[t] - s;
  for (int i = lo; i < hi; ++i) {
    rowstart[i] = run;
    cursor[i] = run;
    run += degcnt[i];
  }
  if (t == 1023) rowstart[N] = tsum[1023];
}

__global__ __launch_bounds__(256) void fill_k(const int* __restrict__ ei,
                                              int* __restrict__ cursor,
                                              int* __restrict__ csr, int E, int N) {
  int e = blockIdx.x * 256 + threadIdx.x;
  if (e >= E) return;
  int s = ei[e];
  int d = ei[(size_t)E + e];
  if ((unsigned)s >= (unsigned)N || (unsigned)d >= (unsigned)N) return;
  int pos = atomicAdd(&cursor[d], 1);
  csr[pos] = s;
}

// ---------------- conversions ----------------

// x fp32 [N,128] -> bf16; thread handles 4 elems
__global__ __launch_bounds__(256) void convx_k(const float* __restrict__ x,
                                               unsigned short* __restrict__ xb, int n4) {
  int t = blockIdx.x * 256 + threadIdx.x;
  if (t >= n4) return;
  float4 v = reinterpret_cast<const float4*>(x)[t];
  ushort4 o;
  o.x = f2bf(v.x); o.y = f2bf(v.y); o.z = f2bf(v.z); o.w = f2bf(v.w);
  reinterpret_cast<ushort4*>(xb)[t] = o;
}

// weight prep: Wt[n][k]=W[k][n]; gwih/gwhh straight cast; lw row-select i,g,o; lbias combine
__global__ __launch_bounds__(256) void prepw_k(
    const float* __restrict__ W, const float* __restrict__ gwih,
    const float* __restrict__ gwhh, const float* __restrict__ lwih,
    const float* __restrict__ lbih, const float* __restrict__ lbhh,
    unsigned short* __restrict__ Wt, unsigned short* __restrict__ gwihb,
    unsigned short* __restrict__ gwhhb, unsigned short* __restrict__ lwb,
    float* __restrict__ lbias) {
  int t = blockIdx.x * 256 + threadIdx.x;
  if (t < 16384) {  // Wt
    int n = t >> 7, k = t & 127;
    Wt[t] = f2bf(W[(size_t)k * 128 + n]);
    return;
  }
  t -= 16384;
  if (t < 49152) { gwihb[t] = f2bf(gwih[t]); return; }
  t -= 49152;
  if (t < 49152) { gwhhb[t] = f2bf(gwhh[t]); return; }
  t -= 49152;
  if (t < 49152) {  // lw select rows {0-127, 256-511}
    int j = t >> 7, k = t & 127;
    int jm = j < 128 ? j : j + 128;
    lwb[t] = f2bf(lwih[(size_t)jm * 128 + k]);
    return;
  }
  t -= 49152;
  if (t < 384) {
    int jm = t < 128 ? t : t + 128;
    lbias[t] = lbih[jm] + lbhh[jm];
  }
}

// ---------------- gather (emits bf16) ----------------

// one wave per dst node: xaggb[d] = bf16(mean of x[src]); lane holds float2
__global__ __launch_bounds__(256) void gather_x_k(const int* __restrict__ csr,
                                                  const int* __restrict__ rowstart,
                                                  const float* __restrict__ x,
                                                  unsigned short* __restrict__ xaggb, int N) {
  int w = (int)(((long long)blockIdx.x * 256 + threadIdx.x) >> 6);
  if (w >= N) return;
  int lane = threadIdx.x & 63;
  int beg = rowstart[w], end = rowstart[w + 1];
  const float2* x2 = reinterpret_cast<const float2*>(x);
  float ax = 0.f, ay = 0.f;
  int j = beg;
  for (; j + 4 <= end; j += 4) {
    int s0 = csr[j], s1 = csr[j + 1], s2 = csr[j + 2], s3 = csr[j + 3];
    float2 v0 = x2[(size_t)s0 * 64 + lane];
    float2 v1 = x2[(size_t)s1 * 64 + lane];
    float2 v2 = x2[(size_t)s2 * 64 + lane];
    float2 v3 = x2[(size_t)s3 * 64 + lane];
    ax += v0.x + v1.x + v2.x + v3.x;
    ay += v0.y + v1.y + v2.y + v3.y;
  }
  for (; j < end; ++j) {
    int s = csr[j];
    float2 v = x2[(size_t)s * 64 + lane];
    ax += v.x;
    ay += v.y;
  }
  float scale = 1.0f / fmaxf((float)(end - beg), 1.0f);
  ushort2 o;
  o.x = f2bf(ax * scale);
  o.y = f2bf(ay * scale);
  reinterpret_cast<ushort2*>(xaggb)[(size_t)w * 64 + lane] = o;
}

// ---------------- bf16 MFMA GEMM (NT, K=128) ----------------
// C[nrows,M] = A[nrows,128] @ B[M,128]^T + bias; OUTBF16 selects bf16/fp32 C.
// 256 thr = 4 waves; tile 64x64; wave w owns rows [w*16,w*16+16), all 64 cols.
// A frags direct from global (lane: 16B = 8 contig bf16); B staged in LDS (pad 136).
template <bool OUTBF16>
__global__ __launch_bounds__(256) void gemm_bf16_k(
    const unsigned short* __restrict__ A, const unsigned short* __restrict__ B,
    const float* __restrict__ bias, void* __restrict__ C, int nrows, int M) {
  __shared__ unsigned short Bs[64][136];  // pad: b128 reads land 2-way (free)
  const int tid = threadIdx.x;
  const int w = tid >> 6, lane = tid & 63;
  const int q = lane >> 4, r = lane & 15;
  const int row0 = blockIdx.y * 64;
  const int col0 = blockIdx.x * 64;

  // stage B tile: 64 rows x 128 k (16 KB)
#pragma unroll
  for (int i = 0; i < 4; ++i) {
    int idx = i * 256 + tid;  // 0..1023
    int c = idx >> 4, kq = idx & 15;
    uint4 v = *reinterpret_cast<const uint4*>(&B[((size_t)(col0 + c)) * HD + kq * 8]);
    *reinterpret_cast<uint4*>(&Bs[c][kq * 8]) = v;
  }
  __syncthreads();

  int arow = row0 + (w << 4) + r;
  int ar = arow < nrows ? arow : nrows - 1;  // clamp; stores guarded below
  const unsigned short* Ap = A + (size_t)ar * HD + q * 8;

  f32x4 acc[4];
#pragma unroll
  for (int cb = 0; cb < 4; ++cb) acc[cb] = (f32x4)0.f;

#pragma unroll
  for (int ks = 0; ks < 4; ++ks) {
    short8 af = *reinterpret_cast<const short8*>(Ap + ks * 32);
#pragma unroll
    for (int cb = 0; cb < 4; ++cb) {
      short8 bf = *reinterpret_cast<const short8*>(&Bs[cb * 16 + r][ks * 32 + q * 8]);
      acc[cb] = __builtin_amdgcn_mfma_f32_16x16x32_bf16(af, bf, acc[cb], 0, 0, 0);
    }
  }

  // C/D layout: col = lane&15, row = quad*4 + reg (within 16x16 block)
#pragma unroll
  for (int cb = 0; cb < 4; ++cb) {
    int col = col0 + cb * 16 + r;
    float bv = bias ? bias[col] : 0.f;
#pragma unroll
    for (int reg = 0; reg < 4; ++reg) {
      int row = row0 + (w << 4) + q * 4 + reg;
      if (row < nrows) {
        float v = acc[cb][reg] + bv;
        if (OUTBF16)
          ((unsigned short*)C)[(size_t)row * M + col] = f2bf(v);
        else
          ((float*)C)[(size_t)row * M + col] = v;
      }
    }
  }
}

// ---------------- elementwise (vectorized x4) ----------------

// GRU: hconv (bf16) = (1-z)*n + z*x ; thread handles 4 cols of one row
__global__ __launch_bounds__(256) void ew_gru_k(const float* __restrict__ gi,
                                                const float* __restrict__ gh,
                                                const float* __restrict__ x,
                                                unsigned short* __restrict__ hcb, int t32) {
  int t = blockIdx.x * 256 + threadIdx.x;
  if (t >= t32) return;
  int i = t >> 5, cq = t & 31;
  size_t b = (size_t)i * 384 + cq * 4;
  float4 ir = *reinterpret_cast<const float4*>(gi + b);
  float4 iz = *reinterpret_cast<const float4*>(gi + b + 128);
  float4 in = *reinterpret_cast<const float4*>(gi + b + 256);
  float4 hr = *reinterpret_cast<const float4*>(gh + b);
  float4 hz = *reinterpret_cast<const float4*>(gh + b + 128);
  float4 hn = *reinterpret_cast<const float4*>(gh + b + 256);
  float4 xv = reinterpret_cast<const float4*>(x)[(size_t)i * 32 + cq];
  ushort4 o;
  {
    float rr = sigf(ir.x + hr.x), zz = sigf(iz.x + hz.x);
    float nn = tanhf(in.x + rr * hn.x);
    o.x = f2bf((1.f - zz) * nn + zz * xv.x);
  }
  {
    float rr = sigf(ir.y + hr.y), zz = sigf(iz.y + hz.y);
    float nn = tanhf(in.y + rr * hn.y);
    o.y = f2bf((1.f - zz) * nn + zz * xv.y);
  }
  {
    float rr = sigf(ir.z + hr.z), zz = sigf(iz.z + hz.z);
    float nn = tanhf(in.z + rr * hn.z);
    o.z = f2bf((1.f - zz) * nn + zz * xv.z);
  }
  {
    float rr = sigf(ir.w + hr.w), zz = sigf(iz.w + hz.w);
    float nn = tanhf(in.w + rr * hn.w);
    o.w = f2bf((1.f - zz) * nn + zz * xv.w);
  }
  reinterpret_cast<ushort4*>(hcb)[(size_t)i * 32 + cq] = o;
}

// LSTM (i,g,o; f dead): out = relu(sig(o)*tanh(sig(i)*tanh(g)))
__global__ __launch_bounds__(256) void ew_lstm_k(const float* __restrict__ g3,
                                                 float* __restrict__ out, int t32) {
  int t = blockIdx.x * 256 + threadIdx.x;
  if (t >= t32) return;
  int i = t >> 5, cq = t & 31;
  size_t b = (size_t)i * 384 + cq * 4;
  float4 ig = *reinterpret_cast<const float4*>(g3 + b);
  float4 gg = *reinterpret_cast<const float4*>(g3 + b + 128);
  float4 og = *reinterpret_cast<const float4*>(g3 + b + 256);
  float4 o;
  o.x = fmaxf(sigf(og.x) * tanhf(sigf(ig.x) * tanhf(gg.x)), 0.f);
  o.y = fmaxf(sigf(og.y) * tanhf(sigf(ig.y) * tanhf(gg.y)), 0.f);
  o.z = fmaxf(sigf(og.z) * tanhf(sigf(ig.z) * tanhf(gg.z)), 0.f);
  o.w = fmaxf(sigf(og.w) * tanhf(sigf(ig.w) * tanhf(gg.w)), 0.f);
  reinterpret_cast<float4*>(out)[(size_t)i * 32 + cq] = o;
}

// ---------------- host ----------------

extern "C" void kernel_launch(void* const* d_in, const int* in_sizes, int n_in,
                              void* d_out, int out_size, void* d_ws, size_t ws_size,
                              hipStream_t stream) {
  const float* x = (const float*)d_in[0];
  const int* ei = (const int*)d_in[1];  // [2,E] int32
  const float* W = (const float*)d_in[2];
  const float* gw_ih = (const float*)d_in[3];
  const float* gw_hh = (const float*)d_in[4];
  const float* gb_ih = (const float*)d_in[5];
  const float* gb_hh = (const float*)d_in[6];
  const float* lw_ih = (const float*)d_in[7];
  // d_in[8] = lstm_w_hh: unused (h0 == 0)
  const float* lb_ih = (const float*)d_in[9];
  const float* lb_hh = (const float*)d_in[10];
  float* out = (float*)d_out;

  const int N = in_sizes[0] / HD;
  const int E = in_sizes[1] / 2;
  const size_t nH = (size_t)N * HD;

  const size_t N4 = (size_t)((N + 7) & ~7);
  const size_t N4p = (size_t)((N + 1 + 7) & ~7);  // rowstart: N+1, NO aliasing
  const size_t E4 = (size_t)((E + 3) & ~3);

  char* p = (char*)d_ws;
  int* degcnt = (int*)p;           p += 4 * N4;
  int* rowstart = (int*)p;         p += 4 * N4p;
  int* cursor = (int*)p;           p += 4 * N4;
  int* csr = (int*)p;              p += 4 * E4;
  unsigned short* xb = (unsigned short*)p;     p += 2 * nH;
  unsigned short* xaggb = (unsigned short*)p;  p += 2 * nH;
  unsigned short* Wt = (unsigned short*)p;     p += 2 * 16384;
  unsigned short* gwihb = (unsigned short*)p;  p += 2 * 49152;
  unsigned short* gwhhb = (unsigned short*)p;  p += 2 * 49152;
  unsigned short* lwb = (unsigned short*)p;    p += 2 * 49152;
  float* lbias = (float*)p;                    p += 4 * 384;

  // adaptive chunk (fixed per problem size -> graph-safe)
  size_t fixed = (size_t)(p - (char*)d_ws);
  long long rem = (ws_size > fixed + 1024) ? (long long)(ws_size - fixed - 1024) : 0;
  long long ncl = rem / 3328;  // Acb(256B) + G1(1536B) + G2(1536B) per row
  int Nc;
  if (ncl >= N) Nc = N;
  else {
    Nc = (int)(ncl & ~63LL);
    if (Nc < 64) Nc = 64;
  }
  unsigned short* Acb = (unsigned short*)p;  // bf16 [Nc,128]; reused as hconv
  float* G1 = (float*)(p + 2 * (size_t)Nc * HD);
  float* G2 = G1 + (size_t)Nc * 384;

  dim3 blk(256);

  // CSR build
  zeroi_k<<<(unsigned)((N4 + 255) / 256), blk, 0, stream>>>(degcnt, (int)N4);
  count_k<<<(unsigned)((E + 255) / 256), blk, 0, stream>>>(ei, degcnt, E, N);
  scan_k<<<1, 1024, 0, stream>>>(degcnt, rowstart, cursor, N);
  fill_k<<<(unsigned)((E + 255) / 256), blk, 0, stream>>>(ei, cursor, csr, E, N);

  // conversions
  convx_k<<<(unsigned)((nH / 4 + 255) / 256), blk, 0, stream>>>(x, xb, (int)(nH / 4));
  prepw_k<<<(16384 + 3 * 49152 + 384 + 255) / 256, blk, 0, stream>>>(
      W, gw_ih, gw_hh, lw_ih, lb_ih, lb_hh, Wt, gwihb, gwhhb, lwb, lbias);

  // xaggb = bf16(mean of x[src] per dst)
  long long gthreads = (long long)N * 64;
  gather_x_k<<<(unsigned)((gthreads + 255) / 256), blk, 0, stream>>>(csr, rowstart, x, xaggb, N);

  // chunked: Ac = xagg@Wt^T; gi = Ac@gwih^T; gh = x@gwhh^T; GRU; g3 = hconv@lw^T; LSTM
  for (int r0 = 0; r0 < N; r0 += Nc) {
    int rows = (N - r0 < Nc) ? (N - r0) : Nc;
    dim3 grows((unsigned)((rows + 63) / 64));
    int t32 = rows * 32;

    gemm_bf16_k<true><<<dim3(2, grows.x), blk, 0, stream>>>(
        xaggb + (size_t)r0 * HD, Wt, nullptr, Acb, rows, HD);

    gemm_bf16_k<false><<<dim3(6, grows.x), blk, 0, stream>>>(
        Acb, gwihb, gb_ih, G1, rows, 384);

    gemm_bf16_k<false><<<dim3(6, grows.x), blk, 0, stream>>>(
        xb + (size_t)r0 * HD, gwhhb, gb_hh, G2, rows, 384);

    ew_gru_k<<<(t32 + 255) / 256, blk, 0, stream>>>(
        G1, G2, x + (size_t)r0 * HD, Acb, t32);  // Acb dead after gi GEMM -> hconv

    gemm_bf16_k<false><<<dim3(6, grows.x), blk, 0, stream>>>(
        Acb, lwb, lbias, G1, rows, 384);

    ew_lstm_k<<<(t32 + 255) / 256, blk, 0, stream>>>(G1, out + (size_t)r0 * HD, t32);
  }
}

// Round 8
// 848.190 us; speedup vs baseline: 7.6156x; 1.5583x over previous
//
#include <hip/hip_runtime.h>
#include <math.h>

#define HD 128
#define PB 256  // partition blocks for bucketed CSR build

typedef __attribute__((ext_vector_type(8))) short short8;
typedef __attribute__((ext_vector_type(4))) float f32x4;

__device__ __forceinline__ float sigf(float v) { return 1.0f / (1.0f + __expf(-v)); }

__device__ __forceinline__ unsigned short f2bf(float f) {
  union { float f; unsigned u; } v; v.f = f;
  unsigned r = (v.u + 0x7fffu + ((v.u >> 16) & 1u)) >> 16;
  return (unsigned short)r;
}
__device__ __forceinline__ float bf2f(unsigned short b) {
  union { unsigned u; float f; } v; v.u = ((unsigned)b) << 16;
  return v.f;
}

// ---------------- CSR build ----------------

__global__ __launch_bounds__(256) void zeroi_k(int* __restrict__ p, int n) {
  int t = blockIdx.x * 256 + threadIdx.x;
  if (t < n) p[t] = 0;
}

__global__ __launch_bounds__(256) void count_k(const int* __restrict__ ei,
                                               int* __restrict__ degcnt, int E, int N) {
  int e = blockIdx.x * 256 + threadIdx.x;
  if (e >= E) return;
  int d = ei[(size_t)E + e];
  if ((unsigned)d >= (unsigned)N) return;
  atomicAdd(&degcnt[d], 1);
}

// degcnt[N] -> rowstart[N+1] exclusive scan (single workgroup)
__global__ __launch_bounds__(1024) void scan_k(const int* __restrict__ degcnt,
                                               int* __restrict__ rowstart, int N) {
  __shared__ int tsum[1024];
  const int t = threadIdx.x;
  const int C = (N + 1023) / 1024;
  const int lo = t * C;
  const int hi = (lo + C < N) ? lo + C : N;
  int s = 0;
  for (int i = lo; i < hi; ++i) s += degcnt[i];
  tsum[t] = s;
  __syncthreads();
  for (int off = 1; off < 1024; off <<= 1) {
    int v = (t >= off) ? tsum[t - off] : 0;
    __syncthreads();
    tsum[t] += v;
    __syncthreads();
  }
  int run = tsum[t] - s;
  for (int i = lo; i < hi; ++i) {
    rowstart[i] = run;
    run += degcnt[i];
  }
  if (t == 1023) rowstart[N] = tsum[1023];
}

// pass A: per (partition-block, bucket) histogram. bcnt[b*PB + blk]
__global__ __launch_bounds__(256) void bcount_k(const int* __restrict__ ei,
                                                int* __restrict__ bcnt,
                                                int E, int N, int shift, int NB) {
  __shared__ int h[256];
  const int blk = blockIdx.x, tid = threadIdx.x;
  h[tid] = 0;
  __syncthreads();
  int per = (E + PB - 1) / PB;
  int lo = blk * per;
  int hi = (lo + per < E) ? lo + per : E;
  for (int e = lo + tid; e < hi; e += 256) {
    int d = ei[(size_t)E + e];
    if ((unsigned)d >= (unsigned)N) continue;
    atomicAdd(&h[d >> shift], 1);
  }
  __syncthreads();
  if (tid < NB) bcnt[tid * PB + blk] = h[tid];
}

// in-place exclusive scan of a[0..total); a[total] = grand total (single wg)
__global__ __launch_bounds__(1024) void escan_k(int* __restrict__ a, int total) {
  __shared__ int tsum[1024];
  const int t = threadIdx.x;
  const int C = (total + 1023) / 1024;
  const int lo = t * C;
  const int hi = (lo + C < total) ? lo + C : total;
  int s = 0;
  for (int i = lo; i < hi; ++i) s += a[i];
  tsum[t] = s;
  __syncthreads();
  for (int off = 1; off < 1024; off <<= 1) {
    int v = (t >= off) ? tsum[t - off] : 0;
    __syncthreads();
    tsum[t] += v;
    __syncthreads();
  }
  int run = tsum[t] - s;
  for (int i = lo; i < hi; ++i) {
    int tmp = a[i];
    a[i] = run;
    run += tmp;
  }
  if (t == 1023) a[total] = tsum[1023];
}

// pass C: partition edges into ebuf grouped by bucket (contiguous runs per block)
__global__ __launch_bounds__(256) void bpart_k(const int* __restrict__ ei,
                                               const int* __restrict__ bstart,
                                               int2* __restrict__ ebuf,
                                               int E, int N, int shift, int NB) {
  __shared__ int cur[256];
  const int blk = blockIdx.x, tid = threadIdx.x;
  if (tid < NB) cur[tid] = bstart[tid * PB + blk];
  __syncthreads();
  int per = (E + PB - 1) / PB;
  int lo = blk * per;
  int hi = (lo + per < E) ? lo + per : E;
  for (int e = lo + tid; e < hi; e += 256) {
    int s = ei[e];
    int d = ei[(size_t)E + e];
    if ((unsigned)s >= (unsigned)N || (unsigned)d >= (unsigned)N) continue;
    int p = atomicAdd(&cur[d >> shift], 1);
    ebuf[p] = make_int2(s, d);
  }
}

// pass D: per-bucket csr fill; writes land in a contiguous region per block
__global__ __launch_bounds__(256) void bfill_k(const int2* __restrict__ ebuf,
                                               const int* __restrict__ bstart,
                                               const int* __restrict__ rowstart,
                                               int* __restrict__ csr,
                                               int N, int shift, int NB) {
  __shared__ int cur[2048];
  const int b = blockIdx.x, tid = threadIdx.x;
  const int d0 = b << shift;
  int dmax = d0 + (1 << shift);
  if (dmax > N) dmax = N;
  const int nd = dmax - d0;
  for (int i = tid; i < nd; i += 256) cur[i] = rowstart[d0 + i];
  __syncthreads();
  int beg = bstart[b * PB];
  int end = (b + 1 < NB) ? bstart[(b + 1) * PB] : bstart[NB * PB];
  for (int idx = beg + tid; idx < end; idx += 256) {
    int2 sd = ebuf[idx];
    int p = atomicAdd(&cur[sd.y - d0], 1);
    csr[p] = sd.x;
  }
}

// ---------------- conversions ----------------

__global__ __launch_bounds__(256) void convx_k(const float* __restrict__ x,
                                               unsigned short* __restrict__ xb, int n4) {
  int t = blockIdx.x * 256 + threadIdx.x;
  if (t >= n4) return;
  float4 v = reinterpret_cast<const float4*>(x)[t];
  ushort4 o;
  o.x = f2bf(v.x); o.y = f2bf(v.y); o.z = f2bf(v.z); o.w = f2bf(v.w);
  reinterpret_cast<ushort4*>(xb)[t] = o;
}

__global__ __launch_bounds__(256) void prepw_k(
    const float* __restrict__ W, const float* __restrict__ gwih,
    const float* __restrict__ gwhh, const float* __restrict__ lwih,
    const float* __restrict__ lbih, const float* __restrict__ lbhh,
    unsigned short* __restrict__ Wt, unsigned short* __restrict__ gwihb,
    unsigned short* __restrict__ gwhhb, unsigned short* __restrict__ lwb,
    float* __restrict__ lbias) {
  int t = blockIdx.x * 256 + threadIdx.x;
  if (t < 16384) {  // Wt[n][k] = W[k][n]
    int n = t >> 7, k = t & 127;
    Wt[t] = f2bf(W[(size_t)k * 128 + n]);
    return;
  }
  t -= 16384;
  if (t < 49152) { gwihb[t] = f2bf(gwih[t]); return; }
  t -= 49152;
  if (t < 49152) { gwhhb[t] = f2bf(gwhh[t]); return; }
  t -= 49152;
  if (t < 49152) {  // select i,g,o rows of [512,128]
    int j = t >> 7, k = t & 127;
    int jm = j < 128 ? j : j + 128;
    lwb[t] = f2bf(lwih[(size_t)jm * 128 + k]);
    return;
  }
  t -= 49152;
  if (t < 384) {
    int jm = t < 128 ? t : t + 128;
    lbias[t] = lbih[jm] + lbhh[jm];
  }
}

// ---------------- gather (bf16 in, bf16 out) ----------------

// one wave per dst: xaggb[d] = bf16(mean of xb[src]); lane holds bf16x2 (4B)
__global__ __launch_bounds__(256) void gather_b_k(const int* __restrict__ csr,
                                                  const int* __restrict__ rowstart,
                                                  const unsigned short* __restrict__ xb,
                                                  unsigned short* __restrict__ xaggb, int N) {
  int w = (int)(((long long)blockIdx.x * 256 + threadIdx.x) >> 6);
  if (w >= N) return;
  int lane = threadIdx.x & 63;
  int beg = rowstart[w], end = rowstart[w + 1];
  const unsigned* x1 = reinterpret_cast<const unsigned*>(xb);
  float ax = 0.f, ay = 0.f;
  int j = beg;
  for (; j + 4 <= end; j += 4) {
    int s0 = csr[j], s1 = csr[j + 1], s2 = csr[j + 2], s3 = csr[j + 3];
    unsigned u0 = x1[(size_t)s0 * 64 + lane];
    unsigned u1 = x1[(size_t)s1 * 64 + lane];
    unsigned u2 = x1[(size_t)s2 * 64 + lane];
    unsigned u3 = x1[(size_t)s3 * 64 + lane];
    ax += bf2f((unsigned short)u0) + bf2f((unsigned short)u1) +
          bf2f((unsigned short)u2) + bf2f((unsigned short)u3);
    ay += bf2f((unsigned short)(u0 >> 16)) + bf2f((unsigned short)(u1 >> 16)) +
          bf2f((unsigned short)(u2 >> 16)) + bf2f((unsigned short)(u3 >> 16));
  }
  for (; j < end; ++j) {
    unsigned u = x1[(size_t)csr[j] * 64 + lane];
    ax += bf2f((unsigned short)u);
    ay += bf2f((unsigned short)(u >> 16));
  }
  float scale = 1.0f / fmaxf((float)(end - beg), 1.0f);
  unsigned o = (unsigned)f2bf(ax * scale) | ((unsigned)f2bf(ay * scale) << 16);
  reinterpret_cast<unsigned*>(xaggb)[(size_t)w * 64 + lane] = o;
}

// ---------------- W GEMM (bf16 NT, K=128, bf16 out) ----------------
__global__ __launch_bounds__(256) void gemmw_k(const unsigned short* __restrict__ A,
                                               const unsigned short* __restrict__ B,
                                               unsigned short* __restrict__ C, int nrows) {
  __shared__ unsigned short Bs[64][136];
  const int tid = threadIdx.x;
  const int w = tid >> 6, lane = tid & 63;
  const int q = lane >> 4, r = lane & 15;
  const int row0 = blockIdx.y * 64;
  const int col0 = blockIdx.x * 64;

#pragma unroll
  for (int i = 0; i < 4; ++i) {
    int idx = i * 256 + tid;  // 1024 = 64 cols x 16 kq
    int c = idx >> 4, kq = idx & 15;
    uint4 v = *reinterpret_cast<const uint4*>(&B[((size_t)(col0 + c)) * HD + kq * 8]);
    *reinterpret_cast<uint4*>(&Bs[c][kq * 8]) = v;
  }
  __syncthreads();

  int arow = row0 + (w << 4) + r;
  int ar = arow < nrows ? arow : nrows - 1;
  const unsigned short* Ap = A + (size_t)ar * HD + q * 8;

  f32x4 acc[4];
#pragma unroll
  for (int cb = 0; cb < 4; ++cb) acc[cb] = (f32x4)0.f;

#pragma unroll
  for (int ks = 0; ks < 4; ++ks) {
    short8 af = *reinterpret_cast<const short8*>(Ap + ks * 32);
#pragma unroll
    for (int cb = 0; cb < 4; ++cb) {
      short8 bf = *reinterpret_cast<const short8*>(&Bs[cb * 16 + r][ks * 32 + q * 8]);
      acc[cb] = __builtin_amdgcn_mfma_f32_16x16x32_bf16(af, bf, acc[cb], 0, 0, 0);
    }
  }

#pragma unroll
  for (int cb = 0; cb < 4; ++cb) {
    int col = col0 + cb * 16 + r;
#pragma unroll
    for (int reg = 0; reg < 4; ++reg) {
      int row = row0 + (w << 4) + q * 4 + reg;
      if (row < nrows) C[(size_t)row * HD + col] = f2bf(acc[cb][reg]);
    }
  }
}

// ---------------- fused GRU: hconv = GRU(Ac, x) ----------------
// grid (4, ceil(nrows/64)); tile 64 rows x 32 cols x 6 planes (ir,iz,in,hr,hz,hn)
__global__ __launch_bounds__(256) void gru_fused_k(
    const unsigned short* __restrict__ Acb, const unsigned short* __restrict__ xb,
    const unsigned short* __restrict__ gwihb, const unsigned short* __restrict__ gwhhb,
    const float* __restrict__ gbih, const float* __restrict__ gbhh,
    unsigned short* __restrict__ hconv, int nrows) {
  __shared__ unsigned short Bsm[6][32][136];  // 52 KB; 136-stride -> 2-way (free)
  const int tid = threadIdx.x;
  const int w = tid >> 6, lane = tid & 63;
  const int q = lane >> 4, r = lane & 15;
  const int row0 = blockIdx.y * 64;
  const int c0 = blockIdx.x * 32;

  // stage 6 planes x 32 cols x 128 k = 24576 shorts = 3072 uint4  (12 x 256)
#pragma unroll
  for (int it = 0; it < 12; ++it) {
    int idx = it * 256 + tid;          // 0..3071
    int p = idx >> 9;                  // plane 0..5
    int rem = idx & 511;               // 512 = 32 cols x 16 kq
    int col = rem >> 4, kq = rem & 15; // kq 0..15 covers full k=128
    const unsigned short* src =
        (p < 3) ? gwihb + ((size_t)(p * 128 + c0 + col)) * HD
                : gwhhb + ((size_t)((p - 3) * 128 + c0 + col)) * HD;
    uint4 v = *reinterpret_cast<const uint4*>(src + kq * 8);
    *reinterpret_cast<uint4*>(&Bsm[p][col][kq * 8]) = v;
  }
  __syncthreads();

  int arow = row0 + (w << 4) + r;
  int ar = arow < nrows ? arow : nrows - 1;
  const unsigned short* Aa = Acb + (size_t)ar * HD + q * 8;
  const unsigned short* Ax = xb + (size_t)ar * HD + q * 8;

  f32x4 acc[6][2];
#pragma unroll
  for (int p = 0; p < 6; ++p)
#pragma unroll
    for (int cb = 0; cb < 2; ++cb) acc[p][cb] = (f32x4)0.f;

#pragma unroll
  for (int ks = 0; ks < 4; ++ks) {
    short8 a1 = *reinterpret_cast<const short8*>(Aa + ks * 32);
    short8 a2 = *reinterpret_cast<const short8*>(Ax + ks * 32);
#pragma unroll
    for (int p = 0; p < 6; ++p) {
      short8 af = (p < 3) ? a1 : a2;
#pragma unroll
      for (int cb = 0; cb < 2; ++cb) {
        short8 bf = *reinterpret_cast<const short8*>(&Bsm[p][cb * 16 + r][ks * 32 + q * 8]);
        acc[p][cb] = __builtin_amdgcn_mfma_f32_16x16x32_bf16(af, bf, acc[p][cb], 0, 0, 0);
      }
    }
  }

#pragma unroll
  for (int cb = 0; cb < 2; ++cb) {
    int col = c0 + cb * 16 + r;
    float bir = gbih[col], biz = gbih[col + 128], bin = gbih[col + 256];
    float bhr = gbhh[col], bhz = gbhh[col + 128], bhn = gbhh[col + 256];
#pragma unroll
    for (int reg = 0; reg < 4; ++reg) {
      int row = row0 + (w << 4) + q * 4 + reg;
      if (row < nrows) {
        float ir = acc[0][cb][reg] + bir, iz = acc[1][cb][reg] + biz;
        float inn = acc[2][cb][reg] + bin;
        float hr = acc[3][cb][reg] + bhr, hz = acc[4][cb][reg] + bhz;
        float hn = acc[5][cb][reg] + bhn;
        float rr = sigf(ir + hr), zz = sigf(iz + hz);
        float nn = tanhf(inn + rr * hn);
        float xv = bf2f(xb[(size_t)row * HD + col]);
        hconv[(size_t)row * HD + col] = f2bf((1.f - zz) * nn + zz * xv);
      }
    }
  }
}

// ---------------- fused LSTM: out = relu(sig(o)*tanh(sig(i)*tanh(g))) ----------------
// grid (2, ceil(nrows/64)); tile 64 rows x 64 cols x 3 planes (i,g,o)
__global__ __launch_bounds__(256) void lstm_fused_k(
    const unsigned short* __restrict__ hconv, const unsigned short* __restrict__ lwb,
    const float* __restrict__ lbias, float* __restrict__ out, int nrows) {
  __shared__ unsigned short Bsm[3][64][136];  // 52 KB
  const int tid = threadIdx.x;
  const int w = tid >> 6, lane = tid & 63;
  const int q = lane >> 4, r = lane & 15;
  const int row0 = blockIdx.y * 64;
  const int c0 = blockIdx.x * 64;

  // 3 planes x 64 cols x 16 kq = 3072 uint4 (12 x 256)
#pragma unroll
  for (int it = 0; it < 12; ++it) {
    int idx = it * 256 + tid;
    int p = idx >> 10, rem = idx & 1023;
    int col = rem >> 4, kq = rem & 15;
    uint4 v = *reinterpret_cast<const uint4*>(
        lwb + ((size_t)(p * 128 + c0 + col)) * HD + kq * 8);
    *reinterpret_cast<uint4*>(&Bsm[p][col][kq * 8]) = v;
  }
  __syncthreads();

  int arow = row0 + (w << 4) + r;
  int ar = arow < nrows ? arow : nrows - 1;
  const unsigned short* Ap = hconv + (size_t)ar * HD + q * 8;

  f32x4 acc[3][4];
#pragma unroll
  for (int p = 0; p < 3; ++p)
#pragma unroll
    for (int cb = 0; cb < 4; ++cb) acc[p][cb] = (f32x4)0.f;

#pragma unroll
  for (int ks = 0; ks < 4; ++ks) {
    short8 af = *reinterpret_cast<const short8*>(Ap + ks * 32);
#pragma unroll
    for (int p = 0; p < 3; ++p)
#pragma unroll
      for (int cb = 0; cb < 4; ++cb) {
        short8 bf = *reinterpret_cast<const short8*>(&Bsm[p][cb * 16 + r][ks * 32 + q * 8]);
        acc[p][cb] = __builtin_amdgcn_mfma_f32_16x16x32_bf16(af, bf, acc[p][cb], 0, 0, 0);
      }
  }

#pragma unroll
  for (int cb = 0; cb < 4; ++cb) {
    int col = c0 + cb * 16 + r;
    float bi = lbias[col], bg = lbias[col + 128], bo = lbias[col + 256];
#pragma unroll
    for (int reg = 0; reg < 4; ++reg) {
      int row = row0 + (w << 4) + q * 4 + reg;
      if (row < nrows) {
        float ig = acc[0][cb][reg] + bi;
        float gg = acc[1][cb][reg] + bg;
        float og = acc[2][cb][reg] + bo;
        float cc = sigf(ig) * tanhf(gg);
        out[(size_t)row * HD + col] = fmaxf(sigf(og) * tanhf(cc), 0.f);
      }
    }
  }
}

// ---------------- host ----------------

extern "C" void kernel_launch(void* const* d_in, const int* in_sizes, int n_in,
                              void* d_out, int out_size, void* d_ws, size_t ws_size,
                              hipStream_t stream) {
  const float* x = (const float*)d_in[0];
  const int* ei = (const int*)d_in[1];
  const float* W = (const float*)d_in[2];
  const float* gw_ih = (const float*)d_in[3];
  const float* gw_hh = (const float*)d_in[4];
  const float* gb_ih = (const float*)d_in[5];
  const float* gb_hh = (const float*)d_in[6];
  const float* lw_ih = (const float*)d_in[7];
  const float* lb_ih = (const float*)d_in[9];
  const float* lb_hh = (const float*)d_in[10];
  float* out = (float*)d_out;

  const int N = in_sizes[0] / HD;
  const int E = in_sizes[1] / 2;
  const size_t nH = (size_t)N * HD;

  int shift = 9;
  while (((N + (1 << shift) - 1) >> shift) > 256) ++shift;
  const int NB = (N + (1 << shift) - 1) >> shift;

  const size_t N4 = (size_t)((N + 7) & ~7);
  const size_t N4p = (size_t)((N + 1 + 7) & ~7);
  const size_t E4 = (size_t)((E + 3) & ~3);
  const size_t BC = (size_t)NB * PB + 8;

  // ws layout: [degcnt][rowstart][bcnt][csr][ebuf|xb][Acb][hconv][weights]
  char* p = (char*)d_ws;
  int* degcnt = (int*)p;    p += 4 * N4;
  int* rowstart = (int*)p;  p += 4 * N4p;
  int* bcnt = (int*)p;      p += 4 * BC;
  int* csr = (int*)p;       p += 4 * E4;
  size_t sz_eb = 8 * E4, sz_xb = 2 * nH;
  int2* ebuf = (int2*)p;                      // dead after bfill_k
  unsigned short* xb = (unsigned short*)p;    // written by convx_k after
  p += (sz_eb > sz_xb ? sz_eb : sz_xb);
  unsigned short* Acb = (unsigned short*)p;    p += 2 * nH;
  unsigned short* hconv = (unsigned short*)p;  p += 2 * nH;
  unsigned short* Wt = (unsigned short*)p;     p += 2 * 16384;
  unsigned short* gwihb = (unsigned short*)p;  p += 2 * 49152;
  unsigned short* gwhhb = (unsigned short*)p;  p += 2 * 49152;
  unsigned short* lwb = (unsigned short*)p;    p += 2 * 49152;
  float* lbias = (float*)p;                    p += 4 * 384;

  unsigned short* xaggb = (unsigned short*)d_out;  // consumed before out written

  dim3 blk(256);
  unsigned rb = (unsigned)((N + 63) / 64);

  // CSR build (bucketed)
  zeroi_k<<<(unsigned)((N4 + 255) / 256), blk, 0, stream>>>(degcnt, (int)N4);
  count_k<<<(unsigned)((E + 255) / 256), blk, 0, stream>>>(ei, degcnt, E, N);
  scan_k<<<1, 1024, 0, stream>>>(degcnt, rowstart, N);
  bcount_k<<<PB, blk, 0, stream>>>(ei, bcnt, E, N, shift, NB);
  escan_k<<<1, 1024, 0, stream>>>(bcnt, NB * PB);
  bpart_k<<<PB, blk, 0, stream>>>(ei, bcnt, ebuf, E, N, shift, NB);
  bfill_k<<<NB, blk, 0, stream>>>(ebuf, bcnt, rowstart, csr, N, shift, NB);

  // conversions (xb overwrites ebuf - ebuf dead after bfill)
  convx_k<<<(unsigned)((nH / 4 + 255) / 256), blk, 0, stream>>>(x, xb, (int)(nH / 4));
  prepw_k<<<(16384 + 3 * 49152 + 384 + 255) / 256, blk, 0, stream>>>(
      W, gw_ih, gw_hh, lw_ih, lb_ih, lb_hh, Wt, gwihb, gwhhb, lwb, lbias);

  // aggregation
  long long gthreads = (long long)N * 64;
  gather_b_k<<<(unsigned)((gthreads + 255) / 256), blk, 0, stream>>>(
      csr, rowstart, xb, xaggb, N);

  // Ac = xagg @ W  (via Wt, NT)
  gemmw_k<<<dim3(2, rb), blk, 0, stream>>>(xaggb, Wt, Acb, N);

  // hconv = GRU(Ac, x)  [fused GEMMs + elementwise]
  gru_fused_k<<<dim3(4, rb), blk, 0, stream>>>(
      Acb, xb, gwihb, gwhhb, gb_ih, gb_hh, hconv, N);

  // out = LSTM(hconv)  [fused GEMM + elementwise]
  lstm_fused_k<<<dim3(2, rb), blk, 0, stream>>>(hconv, lwb, lbias, out, N);
}

// Round 9
// 520.798 us; speedup vs baseline: 12.4031x; 1.6286x over previous
//
#include <hip/hip_runtime.h>
#include <math.h>

#define HD 128
#define PB 256   // partition blocks for bucketed CSR build
#define SCB 4096 // elements per block in multi-block scan

typedef __attribute__((ext_vector_type(8))) short short8;
typedef __attribute__((ext_vector_type(4))) float f32x4;

__device__ __forceinline__ float sigf(float v) { return 1.0f / (1.0f + __expf(-v)); }

__device__ __forceinline__ unsigned short f2bf(float f) {
  union { float f; unsigned u; } v; v.f = f;
  unsigned r = (v.u + 0x7fffu + ((v.u >> 16) & 1u)) >> 16;
  return (unsigned short)r;
}
__device__ __forceinline__ float bf2f(unsigned short b) {
  union { unsigned u; float f; } v; v.u = ((unsigned)b) << 16;
  return v.f;
}

// ---------------- CSR build ----------------

// pass A: per (partition-block, bucket) histogram. bcnt[bucket*PB + blk]
__global__ __launch_bounds__(256) void bcount_k(const int* __restrict__ ei,
                                                int* __restrict__ bcnt,
                                                int E, int N, int shift, int NB) {
  __shared__ int h[256];
  const int blk = blockIdx.x, tid = threadIdx.x;
  h[tid] = 0;
  __syncthreads();
  int per = (E + PB - 1) / PB;
  int lo = blk * per;
  int hi = (lo + per < E) ? lo + per : E;
  for (int e = lo + tid; e < hi; e += 256) {
    int d = ei[(size_t)E + e];
    if ((unsigned)d >= (unsigned)N) continue;
    atomicAdd(&h[d >> shift], 1);
  }
  __syncthreads();
  if (tid < NB) bcnt[tid * PB + blk] = h[tid];
}

// multi-block exclusive scan of a[0..total); a[total] = grand total
__global__ __launch_bounds__(256) void scan1_k(const int* __restrict__ a,
                                               int* __restrict__ bsums, int total) {
  __shared__ int ts[256];
  int b = blockIdx.x, tid = threadIdx.x;
  int lo = b * SCB + tid * 16;
  int s = 0;
#pragma unroll
  for (int i = 0; i < 16; ++i) {
    int idx = lo + i;
    if (idx < total) s += a[idx];
  }
  ts[tid] = s;
  __syncthreads();
  for (int off = 128; off > 0; off >>= 1) {
    if (tid < off) ts[tid] += ts[tid + off];
    __syncthreads();
  }
  if (tid == 0) bsums[b] = ts[0];
}

__global__ __launch_bounds__(256) void scan2_k(int* __restrict__ bsums, int nb) {
  __shared__ int ts[256];
  int tid = threadIdx.x;
  int v = (tid < nb) ? bsums[tid] : 0;
  ts[tid] = v;
  __syncthreads();
  for (int off = 1; off < 256; off <<= 1) {
    int u = (tid >= off) ? ts[tid - off] : 0;
    __syncthreads();
    ts[tid] += u;
    __syncthreads();
  }
  if (tid < nb) bsums[tid] = ts[tid] - v;  // exclusive
}

__global__ __launch_bounds__(256) void scan3_k(int* __restrict__ a,
                                               const int* __restrict__ bsums,
                                               int total, int nblk) {
  __shared__ int ts[256];
  int b = blockIdx.x, tid = threadIdx.x;
  int lo = b * SCB + tid * 16;
  int pre[16];
  int s = 0;
#pragma unroll
  for (int i = 0; i < 16; ++i) {
    int idx = lo + i;
    int xv = (idx < total) ? a[idx] : 0;
    pre[i] = s;
    s += xv;
  }
  ts[tid] = s;
  __syncthreads();
  for (int off = 1; off < 256; off <<= 1) {
    int u = (tid >= off) ? ts[tid - off] : 0;
    __syncthreads();
    ts[tid] += u;
    __syncthreads();
  }
  int off0 = ts[tid] - s + bsums[b];
#pragma unroll
  for (int i = 0; i < 16; ++i) {
    int idx = lo + i;
    if (idx < total) a[idx] = off0 + pre[i];
  }
  if (b == nblk - 1 && tid == 255) a[total] = off0 + s;  // grand total
}

// pass C: partition edges into ebuf grouped by bucket (contiguous runs per block)
__global__ __launch_bounds__(256) void bpart_k(const int* __restrict__ ei,
                                               const int* __restrict__ bstart,
                                               int2* __restrict__ ebuf,
                                               int E, int N, int shift, int NB) {
  __shared__ int cur[256];
  const int blk = blockIdx.x, tid = threadIdx.x;
  if (tid < NB) cur[tid] = bstart[tid * PB + blk];
  __syncthreads();
  int per = (E + PB - 1) / PB;
  int lo = blk * per;
  int hi = (lo + per < E) ? lo + per : E;
  for (int e = lo + tid; e < hi; e += 256) {
    int s = ei[e];
    int d = ei[(size_t)E + e];
    if ((unsigned)s >= (unsigned)N || (unsigned)d >= (unsigned)N) continue;
    int p = atomicAdd(&cur[d >> shift], 1);
    ebuf[p] = make_int2(s, d);
  }
}

// pass D: per-bucket: count per-dst in LDS, LDS-scan -> rowstart, place edges.
// bstart[b*PB] is the bucket's global edge base (scan makes this exact).
__global__ __launch_bounds__(256) void bfill2_k(const int2* __restrict__ ebuf,
                                                const int* __restrict__ bstart,
                                                int* __restrict__ rowstart,
                                                int* __restrict__ csr,
                                                int N, int shift, int NB) {
  __shared__ int cnt[2048];
  __shared__ int tsum[256];
  const int b = blockIdx.x, tid = threadIdx.x;
  const int d0 = b << shift;
  int dmax = d0 + (1 << shift);
  if (dmax > N) dmax = N;
  const int nd = dmax - d0;
  for (int i = tid; i < nd; i += 256) cnt[i] = 0;
  __syncthreads();
  const int base = bstart[b * PB];
  const int end = bstart[(b + 1) * PB];  // b=NB-1 -> bstart[NB*PB] = grand total
  for (int idx = base + tid; idx < end; idx += 256)
    atomicAdd(&cnt[ebuf[idx].y - d0], 1);
  __syncthreads();
  // exclusive scan of cnt[0..nd): contiguous chunk per thread + 256-wide HS scan
  const int C = (nd + 255) / 256;  // <= 8
  int lo = tid * C;
  int hi = (lo + C < nd) ? lo + C : nd;
  int loc[8];
  int s = 0;
  for (int i = lo; i < hi; ++i) {
    loc[i - lo] = cnt[i];
    s += cnt[i];
  }
  tsum[tid] = s;
  __syncthreads();
  for (int off = 1; off < 256; off <<= 1) {
    int u = (tid >= off) ? tsum[tid - off] : 0;
    __syncthreads();
    tsum[tid] += u;
    __syncthreads();
  }
  int run = tsum[tid] - s + base;
  for (int i = lo; i < hi; ++i) {
    rowstart[d0 + i] = run;
    cnt[i] = run;  // becomes the cursor
    run += loc[i - lo];
  }
  if (b == NB - 1 && tid == 255) rowstart[N] = end;
  __syncthreads();
  for (int idx = base + tid; idx < end; idx += 256) {
    int2 sd = ebuf[idx];
    int p = atomicAdd(&cnt[sd.y - d0], 1);
    csr[p] = sd.x;
  }
}

// ---------------- conversions ----------------

__global__ __launch_bounds__(256) void convx_k(const float* __restrict__ x,
                                               unsigned short* __restrict__ xb, int n4) {
  int t = blockIdx.x * 256 + threadIdx.x;
  if (t >= n4) return;
  float4 v = reinterpret_cast<const float4*>(x)[t];
  ushort4 o;
  o.x = f2bf(v.x); o.y = f2bf(v.y); o.z = f2bf(v.z); o.w = f2bf(v.w);
  reinterpret_cast<ushort4*>(xb)[t] = o;
}

__global__ __launch_bounds__(256) void prepw_k(
    const float* __restrict__ W, const float* __restrict__ gwih,
    const float* __restrict__ gwhh, const float* __restrict__ lwih,
    const float* __restrict__ lbih, const float* __restrict__ lbhh,
    unsigned short* __restrict__ Wt, unsigned short* __restrict__ gwihb,
    unsigned short* __restrict__ gwhhb, unsigned short* __restrict__ lwb,
    float* __restrict__ lbias) {
  int t = blockIdx.x * 256 + threadIdx.x;
  if (t < 16384) {  // Wt[n][k] = W[k][n]
    int n = t >> 7, k = t & 127;
    Wt[t] = f2bf(W[(size_t)k * 128 + n]);
    return;
  }
  t -= 16384;
  if (t < 49152) { gwihb[t] = f2bf(gwih[t]); return; }
  t -= 49152;
  if (t < 49152) { gwhhb[t] = f2bf(gwhh[t]); return; }
  t -= 49152;
  if (t < 49152) {  // select i,g,o rows of [512,128]
    int j = t >> 7, k = t & 127;
    int jm = j < 128 ? j : j + 128;
    lwb[t] = f2bf(lwih[(size_t)jm * 128 + k]);
    return;
  }
  t -= 49152;
  if (t < 384) {
    int jm = t < 128 ? t : t + 128;
    lbias[t] = lbih[jm] + lbhh[jm];
  }
}

// ---------------- gather (bf16 in, bf16 out) ----------------

__global__ __launch_bounds__(256) void gather_b_k(const int* __restrict__ csr,
                                                  const int* __restrict__ rowstart,
                                                  const unsigned short* __restrict__ xb,
                                                  unsigned short* __restrict__ xaggb, int N) {
  int w = (int)(((long long)blockIdx.x * 256 + threadIdx.x) >> 6);
  if (w >= N) return;
  int lane = threadIdx.x & 63;
  int beg = rowstart[w], end = rowstart[w + 1];
  const unsigned* x1 = reinterpret_cast<const unsigned*>(xb);
  float ax = 0.f, ay = 0.f;
  int j = beg;
  for (; j + 4 <= end; j += 4) {
    int s0 = csr[j], s1 = csr[j + 1], s2 = csr[j + 2], s3 = csr[j + 3];
    unsigned u0 = x1[(size_t)s0 * 64 + lane];
    unsigned u1 = x1[(size_t)s1 * 64 + lane];
    unsigned u2 = x1[(size_t)s2 * 64 + lane];
    unsigned u3 = x1[(size_t)s3 * 64 + lane];
    ax += bf2f((unsigned short)u0) + bf2f((unsigned short)u1) +
          bf2f((unsigned short)u2) + bf2f((unsigned short)u3);
    ay += bf2f((unsigned short)(u0 >> 16)) + bf2f((unsigned short)(u1 >> 16)) +
          bf2f((unsigned short)(u2 >> 16)) + bf2f((unsigned short)(u3 >> 16));
  }
  for (; j < end; ++j) {
    unsigned u = x1[(size_t)csr[j] * 64 + lane];
    ax += bf2f((unsigned short)u);
    ay += bf2f((unsigned short)(u >> 16));
  }
  float scale = 1.0f / fmaxf((float)(end - beg), 1.0f);
  unsigned o = (unsigned)f2bf(ax * scale) | ((unsigned)f2bf(ay * scale) << 16);
  reinterpret_cast<unsigned*>(xaggb)[(size_t)w * 64 + lane] = o;
}

// ---------------- W GEMM (bf16 NT, K=128, bf16 out) ----------------
__global__ __launch_bounds__(256) void gemmw_k(const unsigned short* __restrict__ A,
                                               const unsigned short* __restrict__ B,
                                               unsigned short* __restrict__ C, int nrows) {
  __shared__ unsigned short Bs[64][136];
  const int tid = threadIdx.x;
  const int w = tid >> 6, lane = tid & 63;
  const int q = lane >> 4, r = lane & 15;
  const int row0 = blockIdx.y * 64;
  const int col0 = blockIdx.x * 64;

#pragma unroll
  for (int i = 0; i < 4; ++i) {
    int idx = i * 256 + tid;
    int c = idx >> 4, kq = idx & 15;
    uint4 v = *reinterpret_cast<const uint4*>(&B[((size_t)(col0 + c)) * HD + kq * 8]);
    *reinterpret_cast<uint4*>(&Bs[c][kq * 8]) = v;
  }
  __syncthreads();

  int arow = row0 + (w << 4) + r;
  int ar = arow < nrows ? arow : nrows - 1;
  const unsigned short* Ap = A + (size_t)ar * HD + q * 8;

  f32x4 acc[4];
#pragma unroll
  for (int cb = 0; cb < 4; ++cb) acc[cb] = (f32x4)0.f;

#pragma unroll
  for (int ks = 0; ks < 4; ++ks) {
    short8 af = *reinterpret_cast<const short8*>(Ap + ks * 32);
#pragma unroll
    for (int cb = 0; cb < 4; ++cb) {
      short8 bf = *reinterpret_cast<const short8*>(&Bs[cb * 16 + r][ks * 32 + q * 8]);
      acc[cb] = __builtin_amdgcn_mfma_f32_16x16x32_bf16(af, bf, acc[cb], 0, 0, 0);
    }
  }

#pragma unroll
  for (int cb = 0; cb < 4; ++cb) {
    int col = col0 + cb * 16 + r;
#pragma unroll
    for (int reg = 0; reg < 4; ++reg) {
      int row = row0 + (w << 4) + q * 4 + reg;
      if (row < nrows) C[(size_t)row * HD + col] = f2bf(acc[cb][reg]);
    }
  }
}

// ---------------- fused GRU ----------------
__global__ __launch_bounds__(256) void gru_fused_k(
    const unsigned short* __restrict__ Acb, const unsigned short* __restrict__ xb,
    const unsigned short* __restrict__ gwihb, const unsigned short* __restrict__ gwhhb,
    const float* __restrict__ gbih, const float* __restrict__ gbhh,
    unsigned short* __restrict__ hconv, int nrows) {
  __shared__ unsigned short Bsm[6][32][136];
  const int tid = threadIdx.x;
  const int w = tid >> 6, lane = tid & 63;
  const int q = lane >> 4, r = lane & 15;
  const int row0 = blockIdx.y * 64;
  const int c0 = blockIdx.x * 32;

  // 6 planes x 32 cols x 16 kq = 3072 uint4 (12 x 256)
#pragma unroll
  for (int it = 0; it < 12; ++it) {
    int idx = it * 256 + tid;
    int p = idx >> 9;
    int rem = idx & 511;
    int col = rem >> 4, kq = rem & 15;
    const unsigned short* src =
        (p < 3) ? gwihb + ((size_t)(p * 128 + c0 + col)) * HD
                : gwhhb + ((size_t)((p - 3) * 128 + c0 + col)) * HD;
    uint4 v = *reinterpret_cast<const uint4*>(src + kq * 8);
    *reinterpret_cast<uint4*>(&Bsm[p][col][kq * 8]) = v;
  }
  __syncthreads();

  int arow = row0 + (w << 4) + r;
  int ar = arow < nrows ? arow : nrows - 1;
  const unsigned short* Aa = Acb + (size_t)ar * HD + q * 8;
  const unsigned short* Ax = xb + (size_t)ar * HD + q * 8;

  f32x4 acc[6][2];
#pragma unroll
  for (int p = 0; p < 6; ++p)
#pragma unroll
    for (int cb = 0; cb < 2; ++cb) acc[p][cb] = (f32x4)0.f;

#pragma unroll
  for (int ks = 0; ks < 4; ++ks) {
    short8 a1 = *reinterpret_cast<const short8*>(Aa + ks * 32);
    short8 a2 = *reinterpret_cast<const short8*>(Ax + ks * 32);
#pragma unroll
    for (int p = 0; p < 6; ++p) {
      short8 af = (p < 3) ? a1 : a2;
#pragma unroll
      for (int cb = 0; cb < 2; ++cb) {
        short8 bf = *reinterpret_cast<const short8*>(&Bsm[p][cb * 16 + r][ks * 32 + q * 8]);
        acc[p][cb] = __builtin_amdgcn_mfma_f32_16x16x32_bf16(af, bf, acc[p][cb], 0, 0, 0);
      }
    }
  }

#pragma unroll
  for (int cb = 0; cb < 2; ++cb) {
    int col = c0 + cb * 16 + r;
    float bir = gbih[col], biz = gbih[col + 128], bin = gbih[col + 256];
    float bhr = gbhh[col], bhz = gbhh[col + 128], bhn = gbhh[col + 256];
#pragma unroll
    for (int reg = 0; reg < 4; ++reg) {
      int row = row0 + (w << 4) + q * 4 + reg;
      if (row < nrows) {
        float ir = acc[0][cb][reg] + bir, iz = acc[1][cb][reg] + biz;
        float inn = acc[2][cb][reg] + bin;
        float hr = acc[3][cb][reg] + bhr, hz = acc[4][cb][reg] + bhz;
        float hn = acc[5][cb][reg] + bhn;
        float rr = sigf(ir + hr), zz = sigf(iz + hz);
        float nn = tanhf(inn + rr * hn);
        float xv = bf2f(xb[(size_t)row * HD + col]);
        hconv[(size_t)row * HD + col] = f2bf((1.f - zz) * nn + zz * xv);
      }
    }
  }
}

// ---------------- fused LSTM ----------------
__global__ __launch_bounds__(256) void lstm_fused_k(
    const unsigned short* __restrict__ hconv, const unsigned short* __restrict__ lwb,
    const float* __restrict__ lbias, float* __restrict__ out, int nrows) {
  __shared__ unsigned short Bsm[3][64][136];
  const int tid = threadIdx.x;
  const int w = tid >> 6, lane = tid & 63;
  const int q = lane >> 4, r = lane & 15;
  const int row0 = blockIdx.y * 64;
  const int c0 = blockIdx.x * 64;

#pragma unroll
  for (int it = 0; it < 12; ++it) {
    int idx = it * 256 + tid;
    int p = idx >> 10, rem = idx & 1023;
    int col = rem >> 4, kq = rem & 15;
    uint4 v = *reinterpret_cast<const uint4*>(
        lwb + ((size_t)(p * 128 + c0 + col)) * HD + kq * 8);
    *reinterpret_cast<uint4*>(&Bsm[p][col][kq * 8]) = v;
  }
  __syncthreads();

  int arow = row0 + (w << 4) + r;
  int ar = arow < nrows ? arow : nrows - 1;
  const unsigned short* Ap = hconv + (size_t)ar * HD + q * 8;

  f32x4 acc[3][4];
#pragma unroll
  for (int p = 0; p < 3; ++p)
#pragma unroll
    for (int cb = 0; cb < 4; ++cb) acc[p][cb] = (f32x4)0.f;

#pragma unroll
  for (int ks = 0; ks < 4; ++ks) {
    short8 af = *reinterpret_cast<const short8*>(Ap + ks * 32);
#pragma unroll
    for (int p = 0; p < 3; ++p)
#pragma unroll
      for (int cb = 0; cb < 4; ++cb) {
        short8 bf = *reinterpret_cast<const short8*>(&Bsm[p][cb * 16 + r][ks * 32 + q * 8]);
        acc[p][cb] = __builtin_amdgcn_mfma_f32_16x16x32_bf16(af, bf, acc[p][cb], 0, 0, 0);
      }
  }

#pragma unroll
  for (int cb = 0; cb < 4; ++cb) {
    int col = c0 + cb * 16 + r;
    float bi = lbias[col], bg = lbias[col + 128], bo = lbias[col + 256];
#pragma unroll
    for (int reg = 0; reg < 4; ++reg) {
      int row = row0 + (w << 4) + q * 4 + reg;
      if (row < nrows) {
        float ig = acc[0][cb][reg] + bi;
        float gg = acc[1][cb][reg] + bg;
        float og = acc[2][cb][reg] + bo;
        float cc = sigf(ig) * tanhf(gg);
        out[(size_t)row * HD + col] = fmaxf(sigf(og) * tanhf(cc), 0.f);
      }
    }
  }
}

// ---------------- host ----------------

extern "C" void kernel_launch(void* const* d_in, const int* in_sizes, int n_in,
                              void* d_out, int out_size, void* d_ws, size_t ws_size,
                              hipStream_t stream) {
  const float* x = (const float*)d_in[0];
  const int* ei = (const int*)d_in[1];
  const float* W = (const float*)d_in[2];
  const float* gw_ih = (const float*)d_in[3];
  const float* gw_hh = (const float*)d_in[4];
  const float* gb_ih = (const float*)d_in[5];
  const float* gb_hh = (const float*)d_in[6];
  const float* lw_ih = (const float*)d_in[7];
  const float* lb_ih = (const float*)d_in[9];
  const float* lb_hh = (const float*)d_in[10];
  float* out = (float*)d_out;

  const int N = in_sizes[0] / HD;
  const int E = in_sizes[1] / 2;
  const size_t nH = (size_t)N * HD;

  int shift = 9;
  while (((N + (1 << shift) - 1) >> shift) > 256) ++shift;
  const int NB = (N + (1 << shift) - 1) >> shift;

  const size_t N4p = (size_t)((N + 1 + 7) & ~7);  // rowstart: N+1
  const size_t E4 = (size_t)((E + 3) & ~3);
  const size_t BC = (size_t)NB * PB + 8;
  const int sc_total = NB * PB;
  const int sc_nblk = (sc_total + SCB - 1) / SCB;

  // ws layout: [rowstart][bcnt][bsums][csr][ebuf|xb][Acb][hconv][weights]
  char* p = (char*)d_ws;
  int* rowstart = (int*)p;  p += 4 * N4p;
  int* bcnt = (int*)p;      p += 4 * BC;
  int* bsums = (int*)p;     p += 4 * 64;
  int* csr = (int*)p;       p += 4 * E4;
  size_t sz_eb = 8 * E4, sz_xb = 2 * nH;
  int2* ebuf = (int2*)p;                    // dead after bfill2_k
  unsigned short* xb = (unsigned short*)p;  // written by convx_k after
  p += (sz_eb > sz_xb ? sz_eb : sz_xb);
  unsigned short* Acb = (unsigned short*)p;    p += 2 * nH;
  unsigned short* hconv = (unsigned short*)p;  p += 2 * nH;
  unsigned short* Wt = (unsigned short*)p;     p += 2 * 16384;
  unsigned short* gwihb = (unsigned short*)p;  p += 2 * 49152;
  unsigned short* gwhhb = (unsigned short*)p;  p += 2 * 49152;
  unsigned short* lwb = (unsigned short*)p;    p += 2 * 49152;
  float* lbias = (float*)p;                    p += 4 * 384;

  unsigned short* xaggb = (unsigned short*)d_out;  // consumed before out written

  dim3 blk(256);
  unsigned rb = (unsigned)((N + 63) / 64);

  // CSR build (bucketed, all passes full-width)
  bcount_k<<<PB, blk, 0, stream>>>(ei, bcnt, E, N, shift, NB);
  scan1_k<<<sc_nblk, blk, 0, stream>>>(bcnt, bsums, sc_total);
  scan2_k<<<1, blk, 0, stream>>>(bsums, sc_nblk);
  scan3_k<<<sc_nblk, blk, 0, stream>>>(bcnt, bsums, sc_total, sc_nblk);
  bpart_k<<<PB, blk, 0, stream>>>(ei, bcnt, ebuf, E, N, shift, NB);
  bfill2_k<<<NB, blk, 0, stream>>>(ebuf, bcnt, rowstart, csr, N, shift, NB);

  // conversions (xb overwrites ebuf - ebuf dead after bfill2)
  convx_k<<<(unsigned)((nH / 4 + 255) / 256), blk, 0, stream>>>(x, xb, (int)(nH / 4));
  prepw_k<<<(16384 + 3 * 49152 + 384 + 255) / 256, blk, 0, stream>>>(
      W, gw_ih, gw_hh, lw_ih, lb_ih, lb_hh, Wt, gwihb, gwhhb, lwb, lbias);

  // aggregation
  long long gthreads = (long long)N * 64;
  gather_b_k<<<(unsigned)((gthreads + 255) / 256), blk, 0, stream>>>(
      csr, rowstart, xb, xaggb, N);

  // Ac = xagg @ W
  gemmw_k<<<dim3(2, rb), blk, 0, stream>>>(xaggb, Wt, Acb, N);

  // hconv = GRU(Ac, x)
  gru_fused_k<<<dim3(4, rb), blk, 0, stream>>>(
      Acb, xb, gwihb, gwhhb, gb_ih, gb_hh, hconv, N);

  // out = LSTM(hconv)
  lstm_fused_k<<<dim3(2, rb), blk, 0, stream>>>(hconv, lwb, lbias, out, N);
}

// Round 10
// 511.189 us; speedup vs baseline: 12.6363x; 1.0188x over previous
//
#include <hip/hip_runtime.h>
#include <math.h>

#define HD 128
#define PB 256   // partition blocks for bucketed CSR build
#define SCB 4096 // elements per block in multi-block scan

typedef __attribute__((ext_vector_type(8))) short short8;
typedef __attribute__((ext_vector_type(4))) float f32x4;

__device__ __forceinline__ float sigf(float v) { return 1.0f / (1.0f + __expf(-v)); }

__device__ __forceinline__ unsigned short f2bf(float f) {
  union { float f; unsigned u; } v; v.f = f;
  unsigned r = (v.u + 0x7fffu + ((v.u >> 16) & 1u)) >> 16;
  return (unsigned short)r;
}
__device__ __forceinline__ float bf2f(unsigned short b) {
  union { unsigned u; float f; } v; v.u = ((unsigned)b) << 16;
  return v.f;
}

// ---------------- CSR build ----------------

// pass A: per (partition-block, bucket) histogram. bcnt[bucket*PB + blk]
__global__ __launch_bounds__(256) void bcount_k(const int* __restrict__ ei,
                                                int* __restrict__ bcnt,
                                                int E, int N, int shift, int NB) {
  __shared__ int h[256];
  const int blk = blockIdx.x, tid = threadIdx.x;
  h[tid] = 0;
  __syncthreads();
  int per = (E + PB - 1) / PB;
  int lo = blk * per;
  int hi = (lo + per < E) ? lo + per : E;
  for (int e = lo + tid; e < hi; e += 256) {
    int d = ei[(size_t)E + e];
    if ((unsigned)d >= (unsigned)N) continue;
    atomicAdd(&h[d >> shift], 1);
  }
  __syncthreads();
  if (tid < NB) bcnt[tid * PB + blk] = h[tid];
}

// multi-block exclusive scan of a[0..total); a[total] = grand total
__global__ __launch_bounds__(256) void scan1_k(const int* __restrict__ a,
                                               int* __restrict__ bsums, int total) {
  __shared__ int ts[256];
  int b = blockIdx.x, tid = threadIdx.x;
  int lo = b * SCB + tid * 16;
  int s = 0;
#pragma unroll
  for (int i = 0; i < 16; ++i) {
    int idx = lo + i;
    if (idx < total) s += a[idx];
  }
  ts[tid] = s;
  __syncthreads();
  for (int off = 128; off > 0; off >>= 1) {
    if (tid < off) ts[tid] += ts[tid + off];
    __syncthreads();
  }
  if (tid == 0) bsums[b] = ts[0];
}

__global__ __launch_bounds__(256) void scan2_k(int* __restrict__ bsums, int nb) {
  __shared__ int ts[256];
  int tid = threadIdx.x;
  int v = (tid < nb) ? bsums[tid] : 0;
  ts[tid] = v;
  __syncthreads();
  for (int off = 1; off < 256; off <<= 1) {
    int u = (tid >= off) ? ts[tid - off] : 0;
    __syncthreads();
    ts[tid] += u;
    __syncthreads();
  }
  if (tid < nb) bsums[tid] = ts[tid] - v;  // exclusive
}

__global__ __launch_bounds__(256) void scan3_k(int* __restrict__ a,
                                               const int* __restrict__ bsums,
                                               int total, int nblk) {
  __shared__ int ts[256];
  int b = blockIdx.x, tid = threadIdx.x;
  int lo = b * SCB + tid * 16;
  int pre[16];
  int s = 0;
#pragma unroll
  for (int i = 0; i < 16; ++i) {
    int idx = lo + i;
    int xv = (idx < total) ? a[idx] : 0;
    pre[i] = s;
    s += xv;
  }
  ts[tid] = s;
  __syncthreads();
  for (int off = 1; off < 256; off <<= 1) {
    int u = (tid >= off) ? ts[tid - off] : 0;
    __syncthreads();
    ts[tid] += u;
    __syncthreads();
  }
  int off0 = ts[tid] - s + bsums[b];
#pragma unroll
  for (int i = 0; i < 16; ++i) {
    int idx = lo + i;
    if (idx < total) a[idx] = off0 + pre[i];
  }
  if (b == nblk - 1 && tid == 255) a[total] = off0 + s;  // grand total
}

// pass C: partition edges into ebuf grouped by bucket; packed (dlocal<<sbits)|src
__global__ __launch_bounds__(256) void bpart_k(const int* __restrict__ ei,
                                               const int* __restrict__ bstart,
                                               unsigned* __restrict__ ebuf,
                                               int E, int N, int shift, int NB,
                                               int sbits) {
  __shared__ int cur[256];
  const int blk = blockIdx.x, tid = threadIdx.x;
  if (tid < NB) cur[tid] = bstart[tid * PB + blk];
  __syncthreads();
  int per = (E + PB - 1) / PB;
  int lo = blk * per;
  int hi = (lo + per < E) ? lo + per : E;
  const unsigned dmask = (1u << shift) - 1u;
  for (int e = lo + tid; e < hi; e += 256) {
    int s = ei[e];
    int d = ei[(size_t)E + e];
    if ((unsigned)s >= (unsigned)N || (unsigned)d >= (unsigned)N) continue;
    int p = atomicAdd(&cur[d >> shift], 1);
    ebuf[p] = (((unsigned)d & dmask) << sbits) | (unsigned)s;
  }
}

// pass D: per-bucket: count per-dst in LDS, LDS-scan -> rowstart, place edges.
__global__ __launch_bounds__(256) void bfill2_k(const unsigned* __restrict__ ebuf,
                                                const int* __restrict__ bstart,
                                                int* __restrict__ rowstart,
                                                int* __restrict__ csr,
                                                int N, int shift, int NB, int sbits) {
  __shared__ int cnt[2048];
  __shared__ int tsum[256];
  const int b = blockIdx.x, tid = threadIdx.x;
  const int d0 = b << shift;
  int dmax = d0 + (1 << shift);
  if (dmax > N) dmax = N;
  const int nd = dmax - d0;
  const unsigned smask = (1u << sbits) - 1u;
  for (int i = tid; i < nd; i += 256) cnt[i] = 0;
  __syncthreads();
  const int base = bstart[b * PB];
  const int end = bstart[(b + 1) * PB];  // b=NB-1 -> bstart[NB*PB] = grand total
  for (int idx = base + tid; idx < end; idx += 256)
    atomicAdd(&cnt[ebuf[idx] >> sbits], 1);
  __syncthreads();
  const int C = (nd + 255) / 256;  // <= 8
  int lo = tid * C;
  int hi = (lo + C < nd) ? lo + C : nd;
  int loc[8];
  int s = 0;
  for (int i = lo; i < hi; ++i) {
    loc[i - lo] = cnt[i];
    s += cnt[i];
  }
  tsum[tid] = s;
  __syncthreads();
  for (int off = 1; off < 256; off <<= 1) {
    int u = (tid >= off) ? tsum[tid - off] : 0;
    __syncthreads();
    tsum[tid] += u;
    __syncthreads();
  }
  int run = tsum[tid] - s + base;
  for (int i = lo; i < hi; ++i) {
    rowstart[d0 + i] = run;
    cnt[i] = run;  // becomes the cursor
    run += loc[i - lo];
  }
  if (b == NB - 1 && tid == 255) rowstart[N] = end;
  __syncthreads();
  for (int idx = base + tid; idx < end; idx += 256) {
    unsigned pk = ebuf[idx];
    int p = atomicAdd(&cnt[pk >> sbits], 1);
    csr[p] = (int)(pk & smask);
  }
}

// ---------------- conversions ----------------

__global__ __launch_bounds__(256) void convx_k(const float* __restrict__ x,
                                               unsigned short* __restrict__ xb, int n4) {
  int t = blockIdx.x * 256 + threadIdx.x;
  if (t >= n4) return;
  float4 v = reinterpret_cast<const float4*>(x)[t];
  ushort4 o;
  o.x = f2bf(v.x); o.y = f2bf(v.y); o.z = f2bf(v.z); o.w = f2bf(v.w);
  reinterpret_cast<ushort4*>(xb)[t] = o;
}

__global__ __launch_bounds__(256) void prepw_k(
    const float* __restrict__ W, const float* __restrict__ gwih,
    const float* __restrict__ gwhh, const float* __restrict__ lwih,
    const float* __restrict__ lbih, const float* __restrict__ lbhh,
    unsigned short* __restrict__ Wt, unsigned short* __restrict__ gwihb,
    unsigned short* __restrict__ gwhhb, unsigned short* __restrict__ lwb,
    float* __restrict__ lbias) {
  int t = blockIdx.x * 256 + threadIdx.x;
  if (t < 16384) {  // Wt[n][k] = W[k][n]
    int n = t >> 7, k = t & 127;
    Wt[t] = f2bf(W[(size_t)k * 128 + n]);
    return;
  }
  t -= 16384;
  if (t < 49152) { gwihb[t] = f2bf(gwih[t]); return; }
  t -= 49152;
  if (t < 49152) { gwhhb[t] = f2bf(gwhh[t]); return; }
  t -= 49152;
  if (t < 49152) {  // select i,g,o rows of [512,128]
    int j = t >> 7, k = t & 127;
    int jm = j < 128 ? j : j + 128;
    lwb[t] = f2bf(lwih[(size_t)jm * 128 + k]);
    return;
  }
  t -= 49152;
  if (t < 384) {
    int jm = t < 128 ? t : t + 128;
    lbias[t] = lbih[jm] + lbhh[jm];
  }
}

// ---------------- gather (bf16 in, bf16 out) ----------------
// wave = 4 subgroups of 16 lanes; each subgroup covers one edge row with uint4
// (16B/lane x 16 lanes = 256B row). 8 edges per iteration (2 loads in flight).
// Final: shfl-xor reduce over subgroups; lanes 0..15 store the bf16 row.
__global__ __launch_bounds__(256) void gather_b_k(const int* __restrict__ csr,
                                                  const int* __restrict__ rowstart,
                                                  const unsigned short* __restrict__ xb,
                                                  unsigned short* __restrict__ xaggb, int N) {
  int w = (int)(((long long)blockIdx.x * 256 + threadIdx.x) >> 6);
  if (w >= N) return;
  const int lane = threadIdx.x & 63;
  const int sub = lane >> 4, li = lane & 15;
  const int beg = rowstart[w], end = rowstart[w + 1];
  const uint4* x4 = reinterpret_cast<const uint4*>(xb);  // row = 16 uint4

  float acc[8] = {0.f, 0.f, 0.f, 0.f, 0.f, 0.f, 0.f, 0.f};
#define ACC8(v)                                           \
  {                                                       \
    acc[0] += bf2f((unsigned short)(v).x);                \
    acc[1] += bf2f((unsigned short)((v).x >> 16));        \
    acc[2] += bf2f((unsigned short)(v).y);                \
    acc[3] += bf2f((unsigned short)((v).y >> 16));        \
    acc[4] += bf2f((unsigned short)(v).z);                \
    acc[5] += bf2f((unsigned short)(v).w >> 0 ? (unsigned short)(v).w : (unsigned short)(v).w); \
    acc[5] += 0.f;                                        \
  }
#undef ACC8

  int j = beg;
  for (; j + 8 <= end; j += 8) {
    int s0 = csr[j + sub];
    int s1 = csr[j + 4 + sub];
    uint4 v0 = x4[(size_t)s0 * 16 + li];
    uint4 v1 = x4[(size_t)s1 * 16 + li];
    acc[0] += bf2f((unsigned short)v0.x) + bf2f((unsigned short)v1.x);
    acc[1] += bf2f((unsigned short)(v0.x >> 16)) + bf2f((unsigned short)(v1.x >> 16));
    acc[2] += bf2f((unsigned short)v0.y) + bf2f((unsigned short)v1.y);
    acc[3] += bf2f((unsigned short)(v0.y >> 16)) + bf2f((unsigned short)(v1.y >> 16));
    acc[4] += bf2f((unsigned short)v0.z) + bf2f((unsigned short)v1.z);
    acc[5] += bf2f((unsigned short)(v0.z >> 16)) + bf2f((unsigned short)(v1.z >> 16));
    acc[6] += bf2f((unsigned short)v0.w) + bf2f((unsigned short)v1.w);
    acc[7] += bf2f((unsigned short)(v0.w >> 16)) + bf2f((unsigned short)(v1.w >> 16));
  }
  if (j + 4 <= end) {
    int s0 = csr[j + sub];
    uint4 v0 = x4[(size_t)s0 * 16 + li];
    acc[0] += bf2f((unsigned short)v0.x);
    acc[1] += bf2f((unsigned short)(v0.x >> 16));
    acc[2] += bf2f((unsigned short)v0.y);
    acc[3] += bf2f((unsigned short)(v0.y >> 16));
    acc[4] += bf2f((unsigned short)v0.z);
    acc[5] += bf2f((unsigned short)(v0.z >> 16));
    acc[6] += bf2f((unsigned short)v0.w);
    acc[7] += bf2f((unsigned short)(v0.w >> 16));
    j += 4;
  }
  int rem = end - j;  // 0..3
  if (sub < rem) {
    int s0 = csr[j + sub];
    uint4 v0 = x4[(size_t)s0 * 16 + li];
    acc[0] += bf2f((unsigned short)v0.x);
    acc[1] += bf2f((unsigned short)(v0.x >> 16));
    acc[2] += bf2f((unsigned short)v0.y);
    acc[3] += bf2f((unsigned short)(v0.y >> 16));
    acc[4] += bf2f((unsigned short)v0.z);
    acc[5] += bf2f((unsigned short)(v0.z >> 16));
    acc[6] += bf2f((unsigned short)v0.w);
    acc[7] += bf2f((unsigned short)(v0.w >> 16));
  }

  // reduce across the 4 subgroups (lanes differing in bits 4,5)
#pragma unroll
  for (int i = 0; i < 8; ++i) {
    acc[i] += __shfl_xor(acc[i], 16, 64);
    acc[i] += __shfl_xor(acc[i], 32, 64);
  }

  if (lane < 16) {
    float scale = 1.0f / fmaxf((float)(end - beg), 1.0f);
    uint4 o;
    o.x = (unsigned)f2bf(acc[0] * scale) | ((unsigned)f2bf(acc[1] * scale) << 16);
    o.y = (unsigned)f2bf(acc[2] * scale) | ((unsigned)f2bf(acc[3] * scale) << 16);
    o.z = (unsigned)f2bf(acc[4] * scale) | ((unsigned)f2bf(acc[5] * scale) << 16);
    o.w = (unsigned)f2bf(acc[6] * scale) | ((unsigned)f2bf(acc[7] * scale) << 16);
    reinterpret_cast<uint4*>(xaggb)[(size_t)w * 16 + li] = o;
  }
}

// ---------------- W GEMM (bf16 NT, K=128, bf16 out) ----------------
__global__ __launch_bounds__(256) void gemmw_k(const unsigned short* __restrict__ A,
                                               const unsigned short* __restrict__ B,
                                               unsigned short* __restrict__ C, int nrows) {
  __shared__ unsigned short Bs[64][136];
  const int tid = threadIdx.x;
  const int w = tid >> 6, lane = tid & 63;
  const int q = lane >> 4, r = lane & 15;
  const int row0 = blockIdx.y * 64;
  const int col0 = blockIdx.x * 64;

#pragma unroll
  for (int i = 0; i < 4; ++i) {
    int idx = i * 256 + tid;
    int c = idx >> 4, kq = idx & 15;
    uint4 v = *reinterpret_cast<const uint4*>(&B[((size_t)(col0 + c)) * HD + kq * 8]);
    *reinterpret_cast<uint4*>(&Bs[c][kq * 8]) = v;
  }
  __syncthreads();

  int arow = row0 + (w << 4) + r;
  int ar = arow < nrows ? arow : nrows - 1;
  const unsigned short* Ap = A + (size_t)ar * HD + q * 8;

  f32x4 acc[4];
#pragma unroll
  for (int cb = 0; cb < 4; ++cb) acc[cb] = (f32x4)0.f;

#pragma unroll
  for (int ks = 0; ks < 4; ++ks) {
    short8 af = *reinterpret_cast<const short8*>(Ap + ks * 32);
#pragma unroll
    for (int cb = 0; cb < 4; ++cb) {
      short8 bf = *reinterpret_cast<const short8*>(&Bs[cb * 16 + r][ks * 32 + q * 8]);
      acc[cb] = __builtin_amdgcn_mfma_f32_16x16x32_bf16(af, bf, acc[cb], 0, 0, 0);
    }
  }

#pragma unroll
  for (int cb = 0; cb < 4; ++cb) {
    int col = col0 + cb * 16 + r;
#pragma unroll
    for (int reg = 0; reg < 4; ++reg) {
      int row = row0 + (w << 4) + q * 4 + reg;
      if (row < nrows) C[(size_t)row * HD + col] = f2bf(acc[cb][reg]);
    }
  }
}

// ---------------- fused GRU ----------------
__global__ __launch_bounds__(256) void gru_fused_k(
    const unsigned short* __restrict__ Acb, const unsigned short* __restrict__ xb,
    const unsigned short* __restrict__ gwihb, const unsigned short* __restrict__ gwhhb,
    const float* __restrict__ gbih, const float* __restrict__ gbhh,
    unsigned short* __restrict__ hconv, int nrows) {
  __shared__ unsigned short Bsm[6][32][136];
  const int tid = threadIdx.x;
  const int w = tid >> 6, lane = tid & 63;
  const int q = lane >> 4, r = lane & 15;
  const int row0 = blockIdx.y * 64;
  const int c0 = blockIdx.x * 32;

#pragma unroll
  for (int it = 0; it < 12; ++it) {
    int idx = it * 256 + tid;
    int p = idx >> 9;
    int rem = idx & 511;
    int col = rem >> 4, kq = rem & 15;
    const unsigned short* src =
        (p < 3) ? gwihb + ((size_t)(p * 128 + c0 + col)) * HD
                : gwhhb + ((size_t)((p - 3) * 128 + c0 + col)) * HD;
    uint4 v = *reinterpret_cast<const uint4*>(src + kq * 8);
    *reinterpret_cast<uint4*>(&Bsm[p][col][kq * 8]) = v;
  }
  __syncthreads();

  int arow = row0 + (w << 4) + r;
  int ar = arow < nrows ? arow : nrows - 1;
  const unsigned short* Aa = Acb + (size_t)ar * HD + q * 8;
  const unsigned short* Ax = xb + (size_t)ar * HD + q * 8;

  f32x4 acc[6][2];
#pragma unroll
  for (int p = 0; p < 6; ++p)
#pragma unroll
    for (int cb = 0; cb < 2; ++cb) acc[p][cb] = (f32x4)0.f;

#pragma unroll
  for (int ks = 0; ks < 4; ++ks) {
    short8 a1 = *reinterpret_cast<const short8*>(Aa + ks * 32);
    short8 a2 = *reinterpret_cast<const short8*>(Ax + ks * 32);
#pragma unroll
    for (int p = 0; p < 6; ++p) {
      short8 af = (p < 3) ? a1 : a2;
#pragma unroll
      for (int cb = 0; cb < 2; ++cb) {
        short8 bf = *reinterpret_cast<const short8*>(&Bsm[p][cb * 16 + r][ks * 32 + q * 8]);
        acc[p][cb] = __builtin_amdgcn_mfma_f32_16x16x32_bf16(af, bf, acc[p][cb], 0, 0, 0);
      }
    }
  }

#pragma unroll
  for (int cb = 0; cb < 2; ++cb) {
    int col = c0 + cb * 16 + r;
    float bir = gbih[col], biz = gbih[col + 128], bin = gbih[col + 256];
    float bhr = gbhh[col], bhz = gbhh[col + 128], bhn = gbhh[col + 256];
#pragma unroll
    for (int reg = 0; reg < 4; ++reg) {
      int row = row0 + (w << 4) + q * 4 + reg;
      if (row < nrows) {
        float ir = acc[0][cb][reg] + bir, iz = acc[1][cb][reg] + biz;
        float inn = acc[2][cb][reg] + bin;
        float hr = acc[3][cb][reg] + bhr, hz = acc[4][cb][reg] + bhz;
        float hn = acc[5][cb][reg] + bhn;
        float rr = sigf(ir + hr), zz = sigf(iz + hz);
        float nn = tanhf(inn + rr * hn);
        float xv = bf2f(xb[(size_t)row * HD + col]);
        hconv[(size_t)row * HD + col] = f2bf((1.f - zz) * nn + zz * xv);
      }
    }
  }
}

// ---------------- fused LSTM ----------------
__global__ __launch_bounds__(256) void lstm_fused_k(
    const unsigned short* __restrict__ hconv, const unsigned short* __restrict__ lwb,
    const float* __restrict__ lbias, float* __restrict__ out, int nrows) {
  __shared__ unsigned short Bsm[3][64][136];
  const int tid = threadIdx.x;
  const int w = tid >> 6, lane = tid & 63;
  const int q = lane >> 4, r = lane & 15;
  const int row0 = blockIdx.y * 64;
  const int c0 = blockIdx.x * 64;

#pragma unroll
  for (int it = 0; it < 12; ++it) {
    int idx = it * 256 + tid;
    int p = idx >> 10, rem = idx & 1023;
    int col = rem >> 4, kq = rem & 15;
    uint4 v = *reinterpret_cast<const uint4*>(
        lwb + ((size_t)(p * 128 + c0 + col)) * HD + kq * 8);
    *reinterpret_cast<uint4*>(&Bsm[p][col][kq * 8]) = v;
  }
  __syncthreads();

  int arow = row0 + (w << 4) + r;
  int ar = arow < nrows ? arow : nrows - 1;
  const unsigned short* Ap = hconv + (size_t)ar * HD + q * 8;

  f32x4 acc[3][4];
#pragma unroll
  for (int p = 0; p < 3; ++p)
#pragma unroll
    for (int cb = 0; cb < 4; ++cb) acc[p][cb] = (f32x4)0.f;

#pragma unroll
  for (int ks = 0; ks < 4; ++ks) {
    short8 af = *reinterpret_cast<const short8*>(Ap + ks * 32);
#pragma unroll
    for (int p = 0; p < 3; ++p)
#pragma unroll
      for (int cb = 0; cb < 4; ++cb) {
        short8 bf = *reinterpret_cast<const short8*>(&Bsm[p][cb * 16 + r][ks * 32 + q * 8]);
        acc[p][cb] = __builtin_amdgcn_mfma_f32_16x16x32_bf16(af, bf, acc[p][cb], 0, 0, 0);
      }
  }

#pragma unroll
  for (int cb = 0; cb < 4; ++cb) {
    int col = c0 + cb * 16 + r;
    float bi = lbias[col], bg = lbias[col + 128], bo = lbias[col + 256];
#pragma unroll
    for (int reg = 0; reg < 4; ++reg) {
      int row = row0 + (w << 4) + q * 4 + reg;
      if (row < nrows) {
        float ig = acc[0][cb][reg] + bi;
        float gg = acc[1][cb][reg] + bg;
        float og = acc[2][cb][reg] + bo;
        float cc = sigf(ig) * tanhf(gg);
        out[(size_t)row * HD + col] = fmaxf(sigf(og) * tanhf(cc), 0.f);
      }
    }
  }
}

// ---------------- host ----------------

extern "C" void kernel_launch(void* const* d_in, const int* in_sizes, int n_in,
                              void* d_out, int out_size, void* d_ws, size_t ws_size,
                              hipStream_t stream) {
  const float* x = (const float*)d_in[0];
  const int* ei = (const int*)d_in[1];
  const float* W = (const float*)d_in[2];
  const float* gw_ih = (const float*)d_in[3];
  const float* gw_hh = (const float*)d_in[4];
  const float* gb_ih = (const float*)d_in[5];
  const float* gb_hh = (const float*)d_in[6];
  const float* lw_ih = (const float*)d_in[7];
  const float* lb_ih = (const float*)d_in[9];
  const float* lb_hh = (const float*)d_in[10];
  float* out = (float*)d_out;

  const int N = in_sizes[0] / HD;
  const int E = in_sizes[1] / 2;
  const size_t nH = (size_t)N * HD;

  int shift = 9;
  while (((N + (1 << shift) - 1) >> shift) > 256) ++shift;
  const int NB = (N + (1 << shift) - 1) >> shift;
  const int sbits = 32 - shift;  // src bits in packed ebuf (N=100k << 2^23 OK)

  const size_t N4p = (size_t)((N + 1 + 7) & ~7);  // rowstart: N+1
  const size_t E4 = (size_t)((E + 3) & ~3);
  const size_t BC = (size_t)NB * PB + 8;
  const int sc_total = NB * PB;
  const int sc_nblk = (sc_total + SCB - 1) / SCB;

  // ws layout: [rowstart][bcnt][bsums][csr][ebuf|xb][Acb][hconv][weights]
  char* p = (char*)d_ws;
  int* rowstart = (int*)p;  p += 4 * N4p;
  int* bcnt = (int*)p;      p += 4 * BC;
  int* bsums = (int*)p;     p += 4 * 64;
  int* csr = (int*)p;       p += 4 * E4;
  size_t sz_eb = 4 * E4, sz_xb = 2 * nH;
  unsigned* ebuf = (unsigned*)p;            // dead after bfill2_k
  unsigned short* xb = (unsigned short*)p;  // written by convx_k after
  p += (sz_eb > sz_xb ? sz_eb : sz_xb);
  unsigned short* Acb = (unsigned short*)p;    p += 2 * nH;
  unsigned short* hconv = (unsigned short*)p;  p += 2 * nH;
  unsigned short* Wt = (unsigned short*)p;     p += 2 * 16384;
  unsigned short* gwihb = (unsigned short*)p;  p += 2 * 49152;
  unsigned short* gwhhb = (unsigned short*)p;  p += 2 * 49152;
  unsigned short* lwb = (unsigned short*)p;    p += 2 * 49152;
  float* lbias = (float*)p;                    p += 4 * 384;

  unsigned short* xaggb = (unsigned short*)d_out;  // consumed before out written

  dim3 blk(256);
  unsigned rb = (unsigned)((N + 63) / 64);

  // CSR build (bucketed, all passes full-width)
  bcount_k<<<PB, blk, 0, stream>>>(ei, bcnt, E, N, shift, NB);
  scan1_k<<<sc_nblk, blk, 0, stream>>>(bcnt, bsums, sc_total);
  scan2_k<<<1, blk, 0, stream>>>(bsums, sc_nblk);
  scan3_k<<<sc_nblk, blk, 0, stream>>>(bcnt, bsums, sc_total, sc_nblk);
  bpart_k<<<PB, blk, 0, stream>>>(ei, bcnt, ebuf, E, N, shift, NB, sbits);
  bfill2_k<<<NB, blk, 0, stream>>>(ebuf, bcnt, rowstart, csr, N, shift, NB, sbits);

  // conversions (xb overwrites ebuf - ebuf dead after bfill2)
  convx_k<<<(unsigned)((nH / 4 + 255) / 256), blk, 0, stream>>>(x, xb, (int)(nH / 4));
  prepw_k<<<(16384 + 3 * 49152 + 384 + 255) / 256, blk, 0, stream>>>(
      W, gw_ih, gw_hh, lw_ih, lb_ih, lb_hh, Wt, gwihb, gwhhb, lwb, lbias);

  // aggregation
  long long gthreads = (long long)N * 64;
  gather_b_k<<<(unsigned)((gthreads + 255) / 256), blk, 0, stream>>>(
      csr, rowstart, xb, xaggb, N);

  // Ac = xagg @ W
  gemmw_k<<<dim3(2, rb), blk, 0, stream>>>(xaggb, Wt, Acb, N);

  // hconv = GRU(Ac, x)
  gru_fused_k<<<dim3(4, rb), blk, 0, stream>>>(
      Acb, xb, gwihb, gwhhb, gb_ih, gb_hh, hconv, N);

  // out = LSTM(hconv)
  lstm_fused_k<<<dim3(2, rb), blk, 0, stream>>>(hconv, lwb, lbias, out, N);
}